// Round 1
// baseline (284.340 us; speedup 1.0000x reference)
//
#include <hip/hip_runtime.h>
#include <hip/hip_bf16.h>
#include <cstdint>
#include <cstddef>

typedef __attribute__((ext_vector_type(8))) short short8;
typedef __attribute__((ext_vector_type(4))) short short4_t;
typedef __attribute__((ext_vector_type(4))) float f32x4;

constexpr int B_ = 2, S_ = 2048, H_ = 16, DK_ = 64, DM_ = 1024;

__device__ inline unsigned short f2bf(float x) {
  union { float f; unsigned u; } c; c.f = x;
  unsigned r = c.u + 0x7FFF + ((c.u >> 16) & 1);
  return (unsigned short)(r >> 16);
}

__device__ inline f32x4 mfma16(short8 a, short8 b, f32x4 c) {
  return __builtin_amdgcn_mfma_f32_16x16x32_bf16(a, b, c, 0, 0, 0);
}

// async global->LDS, 16B per lane; LDS dest must be linear (base + lane*16)
__device__ inline void glds16(const unsigned short* g, unsigned short* l) {
  __builtin_amdgcn_global_load_lds(
      (const __attribute__((address_space(1))) unsigned int*)g,
      (__attribute__((address_space(3))) unsigned int*)l, 16, 0, 0);
}

// ---------------- f32 -> bf16 convert ----------------
__global__ __launch_bounds__(256) void cvt_f32_bf16(
    const float* __restrict__ in, unsigned short* __restrict__ out, int n4) {
  int i = blockIdx.x * blockDim.x + threadIdx.x;
  if (i >= n4) return;
  float4 f = ((const float4*)in)[i];
  short4_t o;
  o[0] = (short)f2bf(f.x); o[1] = (short)f2bf(f.y);
  o[2] = (short)f2bf(f.z); o[3] = (short)f2bf(f.w);
  ((short4_t*)out)[i] = o;
}

// ---------------- bf16 GEMM: C[m][n] = sum_k A[m][k]*Bw[n][k] + bias[n] ----
__device__ inline void store_out(float* p, float v) { *p = v; }
__device__ inline void store_out(unsigned short* p, float v) { *p = f2bf(v); }

template <typename OUT_T>
__global__ __launch_bounds__(256) void gemm_bt(
    const unsigned short* __restrict__ A, const unsigned short* __restrict__ Bw,
    const float* __restrict__ bias, OUT_T* __restrict__ C,
    int M, int N, int K) {
  __shared__ unsigned short As[128][64];  // 16 KB
  __shared__ unsigned short Bs[128][64];  // 16 KB

  const int tid = threadIdx.x;
  const int lane = tid & 63, wave = tid >> 6;
  const int li = lane & 15, lg = lane >> 4;
  const int wm = wave >> 1, wn = wave & 1;   // 2x2 waves, 64x64 each
  const int bm = blockIdx.x, bn = blockIdx.y;

  const f32x4 zero4 = {0.f, 0.f, 0.f, 0.f};
  f32x4 acc[4][4];
#pragma unroll
  for (int i = 0; i < 4; i++)
#pragma unroll
    for (int j = 0; j < 4; j++) acc[i][j] = zero4;

  const int stg_row = tid >> 3;        // 0..31
  const int stg_col = (tid & 7) * 8;   // element col (x8 bf16 = 16B)
  const unsigned short* Ag = A + (size_t)(bm * 128 + stg_row) * K + stg_col;
  const unsigned short* Bg = Bw + (size_t)(bn * 128 + stg_row) * K + stg_col;

  for (int kt = 0; kt < K; kt += 64) {
#pragma unroll
    for (int i = 0; i < 4; i++) {
      glds16(Ag + (size_t)(i * 32) * K + kt, &As[i * 32 + stg_row][stg_col]);
      glds16(Bg + (size_t)(i * 32) * K + kt, &Bs[i * 32 + stg_row][stg_col]);
    }
    __syncthreads();   // drains vmcnt -> staged data visible

    short8 af[4][2], bf[4][2];
#pragma unroll
    for (int i = 0; i < 4; i++)
#pragma unroll
      for (int kb = 0; kb < 2; kb++) {
        af[i][kb] = *(const short8*)&As[wm * 64 + i * 16 + li][kb * 32 + lg * 8];
        bf[i][kb] = *(const short8*)&Bs[wn * 64 + i * 16 + li][kb * 32 + lg * 8];
      }
#pragma unroll
    for (int kb = 0; kb < 2; kb++)
#pragma unroll
      for (int i = 0; i < 4; i++)
#pragma unroll
        for (int j = 0; j < 4; j++)
          acc[i][j] = mfma16(af[i][kb], bf[j][kb], acc[i][j]);
    __syncthreads();   // safe to restage next tile
  }

  // epilogue: C/D layout col=lane&15, row=(lane>>4)*4+reg
#pragma unroll
  for (int j = 0; j < 4; j++) {
    int col = bn * 128 + wn * 64 + j * 16 + li;
    float bv = bias[col];
#pragma unroll
    for (int i = 0; i < 4; i++) {
      int row0 = bm * 128 + wm * 64 + i * 16 + lg * 4;
#pragma unroll
      for (int r = 0; r < 4; r++)
        store_out(&C[(size_t)(row0 + r) * N + col], acc[i][j][r] + bv);
    }
  }
}

// ---------------- flash attention ----------------
// q,k,v,ctx layout: [B, S, H, DK] (i.e. [b*S+s][h*64+d], row stride 1024)
__global__ __launch_bounds__(256) void attn_fwd(
    const unsigned short* __restrict__ q, const unsigned short* __restrict__ k,
    const unsigned short* __restrict__ v, unsigned short* __restrict__ ctx) {
  __shared__ unsigned short Ks[64][64];      // [key][dk]  8 KB
  __shared__ unsigned short Vt[64][64];      // [dk][key]  8 KB (transposed)
  __shared__ unsigned short Ps[4][16][64];   // per-wave P 8 KB

  const int tid = threadIdx.x;
  const int lane = tid & 63, wave = tid >> 6;
  const int li = lane & 15, lg = lane >> 4;
  const int qt = blockIdx.x, bh = blockIdx.y;
  const int b = bh >> 4, h = bh & 15;

  // Q fragments for this wave's 16 q-rows (A-operand: row=li, k=lg*8+j)
  const unsigned short* qg =
      q + (size_t)(b * S_ + qt * 64 + wave * 16 + li) * DM_ + h * DK_;
  short8 qf[2];
  qf[0] = *(const short8*)(qg + lg * 8);
  qf[1] = *(const short8*)(qg + 32 + lg * 8);

  const f32x4 zero4 = {0.f, 0.f, 0.f, 0.f};
  f32x4 po[4];
#pragma unroll
  for (int d = 0; d < 4; d++) po[d] = zero4;
  float m_i[4], l_i[4];
#pragma unroll
  for (int r = 0; r < 4; r++) { m_i[r] = -1e30f; l_i[r] = 0.f; }

  const float scale = 0.125f;  // 1/sqrt(64)

  const int stg_row = tid >> 3;
  const int stg_col = (tid & 7) * 8;
  const unsigned short* kg = k + (size_t)(b * S_) * DM_ + h * DK_;
  const int vkey = tid & 63;
  const int vd0 = (tid >> 6) * 16;
  const unsigned short* vg = v + (size_t)(b * S_) * DM_ + h * DK_;

  for (int kt = 0; kt < S_ / 64; kt++) {
    __syncthreads();  // prior tile's reads complete before restage
    // stage K tile (linear -> global_load_lds ok)
    const unsigned short* kgt = kg + (size_t)(kt * 64) * DM_;
    glds16(kgt + (size_t)stg_row * DM_ + stg_col, &Ks[stg_row][stg_col]);
    glds16(kgt + (size_t)(32 + stg_row) * DM_ + stg_col, &Ks[32 + stg_row][stg_col]);
    // stage V transposed (reg round-trip; scattered 2B LDS writes)
    {
      const unsigned short* vp = vg + (size_t)(kt * 64 + vkey) * DM_ + vd0;
      short8 t0 = *(const short8*)(vp);
      short8 t1 = *(const short8*)(vp + 8);
#pragma unroll
      for (int j = 0; j < 8; j++) Vt[vd0 + j][vkey] = (unsigned short)t0[j];
#pragma unroll
      for (int j = 0; j < 8; j++) Vt[vd0 + 8 + j][vkey] = (unsigned short)t1[j];
    }
    __syncthreads();

    // S = Q K^T  (16 rows x 64 keys per wave)
    f32x4 sacc[4];
#pragma unroll
    for (int cb = 0; cb < 4; cb++) sacc[cb] = zero4;
#pragma unroll
    for (int cb = 0; cb < 4; cb++)
#pragma unroll
      for (int kb = 0; kb < 2; kb++) {
        short8 kf = *(const short8*)&Ks[cb * 16 + li][kb * 32 + lg * 8];
        sacc[cb] = mfma16(qf[kb], kf, sacc[cb]);
      }

    // online softmax (rows live across 16-lane groups; reg r -> row lg*4+r)
    float p[4][4];
#pragma unroll
    for (int r = 0; r < 4; r++) {
      float rm = fmaxf(fmaxf(sacc[0][r], sacc[1][r]),
                       fmaxf(sacc[2][r], sacc[3][r]));
      rm = fmaxf(rm, __shfl_xor(rm, 1));
      rm = fmaxf(rm, __shfl_xor(rm, 2));
      rm = fmaxf(rm, __shfl_xor(rm, 4));
      rm = fmaxf(rm, __shfl_xor(rm, 8));
      float mnew = fmaxf(m_i[r], rm * scale);
      float alpha = __expf(m_i[r] - mnew);
      float rs = 0.f;
#pragma unroll
      for (int cb = 0; cb < 4; cb++) {
        float pv = __expf(sacc[cb][r] * scale - mnew);
        p[cb][r] = pv;
        rs += pv;
      }
      rs += __shfl_xor(rs, 1);
      rs += __shfl_xor(rs, 2);
      rs += __shfl_xor(rs, 4);
      rs += __shfl_xor(rs, 8);
      l_i[r] = l_i[r] * alpha + rs;
      m_i[r] = mnew;
#pragma unroll
      for (int d = 0; d < 4; d++) po[d][r] = po[d][r] * alpha;
    }

    // P (C-layout) -> LDS -> A-frag layout (per-wave buffer, no barrier)
#pragma unroll
    for (int cb = 0; cb < 4; cb++)
#pragma unroll
      for (int r = 0; r < 4; r++)
        Ps[wave][lg * 4 + r][cb * 16 + li] = f2bf(p[cb][r]);

    short8 pf0 = *(const short8*)&Ps[wave][li][lg * 8];
    short8 pf1 = *(const short8*)&Ps[wave][li][32 + lg * 8];

    // ctx += P @ V
#pragma unroll
    for (int d = 0; d < 4; d++) {
      short8 vf0 = *(const short8*)&Vt[d * 16 + li][lg * 8];
      short8 vf1 = *(const short8*)&Vt[d * 16 + li][32 + lg * 8];
      po[d] = mfma16(pf0, vf0, po[d]);
      po[d] = mfma16(pf1, vf1, po[d]);
    }
  }

  // epilogue: divide by l, store bf16 ctx in [B,S,H,DK]
  unsigned short* cg =
      ctx + (size_t)(b * S_ + qt * 64 + wave * 16) * DM_ + h * DK_;
#pragma unroll
  for (int d = 0; d < 4; d++)
#pragma unroll
    for (int r = 0; r < 4; r++) {
      int row = lg * 4 + r;
      cg[(size_t)row * DM_ + d * 16 + li] = f2bf(po[d][r] / l_i[r]);
    }
}

// ---------------- launch ----------------
extern "C" void kernel_launch(void* const* d_in, const int* in_sizes, int n_in,
                              void* d_out, int out_size, void* d_ws, size_t ws_size,
                              hipStream_t stream) {
  const float* Q  = (const float*)d_in[0];
  const float* Kx = (const float*)d_in[1];
  const float* V  = (const float*)d_in[2];
  const float* Wq = (const float*)d_in[3];
  const float* bq = (const float*)d_in[4];
  const float* Wk = (const float*)d_in[5];
  const float* bk = (const float*)d_in[6];
  const float* Wv = (const float*)d_in[7];
  const float* bv = (const float*)d_in[8];
  const float* Wo = (const float*)d_in[9];
  const float* bo = (const float*)d_in[10];
  float* out = (float*)d_out;

  char* ws = (char*)d_ws;
  const size_t MB = 1ull << 20;
  unsigned short* Qb  = (unsigned short*)(ws + 0 * MB);
  unsigned short* Kb  = (unsigned short*)(ws + 8 * MB);
  unsigned short* Vb  = (unsigned short*)(ws + 16 * MB);
  unsigned short* Wqb = (unsigned short*)(ws + 24 * MB);
  unsigned short* Wkb = (unsigned short*)(ws + 26 * MB);
  unsigned short* Wvb = (unsigned short*)(ws + 28 * MB);
  unsigned short* Wob = (unsigned short*)(ws + 30 * MB);
  unsigned short* qp  = (unsigned short*)(ws + 32 * MB);
  unsigned short* kp  = (unsigned short*)(ws + 40 * MB);
  unsigned short* vp  = (unsigned short*)(ws + 48 * MB);
  unsigned short* cx  = (unsigned short*)(ws + 56 * MB);  // 64 MB total

  const int nAct = B_ * S_ * DM_;  // 4194304
  const int nW = DM_ * DM_;        // 1048576

  cvt_f32_bf16<<<nAct / 4 / 256, 256, 0, stream>>>(Q, Qb, nAct / 4);
  cvt_f32_bf16<<<nAct / 4 / 256, 256, 0, stream>>>(Kx, Kb, nAct / 4);
  cvt_f32_bf16<<<nAct / 4 / 256, 256, 0, stream>>>(V, Vb, nAct / 4);
  cvt_f32_bf16<<<nW / 4 / 256, 256, 0, stream>>>(Wq, Wqb, nW / 4);
  cvt_f32_bf16<<<nW / 4 / 256, 256, 0, stream>>>(Wk, Wkb, nW / 4);
  cvt_f32_bf16<<<nW / 4 / 256, 256, 0, stream>>>(Wv, Wvb, nW / 4);
  cvt_f32_bf16<<<nW / 4 / 256, 256, 0, stream>>>(Wo, Wob, nW / 4);

  dim3 gg(32, 8);  // M/128 x N/128
  gemm_bt<unsigned short><<<gg, 256, 0, stream>>>(Qb, Wqb, bq, qp, 4096, 1024, 1024);
  gemm_bt<unsigned short><<<gg, 256, 0, stream>>>(Kb, Wkb, bk, kp, 4096, 1024, 1024);
  gemm_bt<unsigned short><<<gg, 256, 0, stream>>>(Vb, Wvb, bv, vp, 4096, 1024, 1024);

  attn_fwd<<<dim3(32, 32), 256, 0, stream>>>(qp, kp, vp, cx);

  gemm_bt<float><<<gg, 256, 0, stream>>>(cx, Wob, bo, out, 4096, 1024, 1024);
}

// Round 2
// 235.758 us; speedup vs baseline: 1.2061x; 1.2061x over previous
//
#include <hip/hip_runtime.h>
#include <hip/hip_bf16.h>
#include <cstdint>
#include <cstddef>

typedef __attribute__((ext_vector_type(8))) short short8;
typedef __attribute__((ext_vector_type(4))) short short4_t;
typedef __attribute__((ext_vector_type(4))) float f32x4;

constexpr int B_ = 2, S_ = 2048, H_ = 16, DK_ = 64, DM_ = 1024;

__device__ inline unsigned short f2bf(float x) {
  union { float f; unsigned u; } c; c.f = x;
  unsigned r = c.u + 0x7FFF + ((c.u >> 16) & 1);
  return (unsigned short)(r >> 16);
}

__device__ inline f32x4 mfma16(short8 a, short8 b, f32x4 c) {
  return __builtin_amdgcn_mfma_f32_16x16x32_bf16(a, b, c, 0, 0, 0);
}

// async global->LDS, 16B per lane; LDS dest must be linear (base + lane*16)
__device__ inline void glds16(const unsigned short* g, unsigned short* l) {
  __builtin_amdgcn_global_load_lds(
      (const __attribute__((address_space(1))) unsigned int*)g,
      (__attribute__((address_space(3))) unsigned int*)l, 16, 0, 0);
}

// ---------------- f32 -> bf16 convert ----------------
__global__ __launch_bounds__(256) void cvt_f32_bf16(
    const float* __restrict__ in, unsigned short* __restrict__ out, int n4) {
  int i = blockIdx.x * blockDim.x + threadIdx.x;
  if (i >= n4) return;
  float4 f = ((const float4*)in)[i];
  short4_t o;
  o[0] = (short)f2bf(f.x); o[1] = (short)f2bf(f.y);
  o[2] = (short)f2bf(f.z); o[3] = (short)f2bf(f.w);
  ((short4_t*)out)[i] = o;
}

// ---------------- bf16 GEMM: C[m][n] = sum_k A[m][k]*Bw[n][k] + bias[n] ----
// 128x64 tile, 4 waves (2x2, 64x32 each), grid (M/128, N/64) = 512 blocks
// -> 2 blocks/CU so barrier drains overlap across blocks.
__device__ inline void store_out(float* p, float v) { *p = v; }
__device__ inline void store_out(unsigned short* p, float v) { *p = f2bf(v); }

template <typename OUT_T>
__global__ __launch_bounds__(256) void gemm_bt(
    const unsigned short* __restrict__ A, const unsigned short* __restrict__ Bw,
    const float* __restrict__ bias, OUT_T* __restrict__ C,
    int M, int N, int K) {
  __shared__ unsigned short As[128][64];  // 16 KB
  __shared__ unsigned short Bs[64][64];   // 8 KB

  const int tid = threadIdx.x;
  const int lane = tid & 63, wave = tid >> 6;
  const int li = lane & 15, lg = lane >> 4;
  const int wm = wave >> 1, wn = wave & 1;   // 2x2 waves; 64x32 per wave
  const int bm = blockIdx.x, bn = blockIdx.y;

  const f32x4 zero4 = {0.f, 0.f, 0.f, 0.f};
  f32x4 acc[4][2];
#pragma unroll
  for (int i = 0; i < 4; i++)
#pragma unroll
    for (int j = 0; j < 2; j++) acc[i][j] = zero4;

  const int stg_row = tid >> 3;        // 0..31
  const int stg_col = (tid & 7) * 8;   // element col (x8 bf16 = 16B)
  const unsigned short* Ag = A + (size_t)(bm * 128 + stg_row) * K + stg_col;
  const unsigned short* Bg = Bw + (size_t)(bn * 64 + stg_row) * K + stg_col;

  for (int kt = 0; kt < K; kt += 64) {
#pragma unroll
    for (int i = 0; i < 4; i++)
      glds16(Ag + (size_t)(i * 32) * K + kt, &As[i * 32 + stg_row][stg_col]);
#pragma unroll
    for (int i = 0; i < 2; i++)
      glds16(Bg + (size_t)(i * 32) * K + kt, &Bs[i * 32 + stg_row][stg_col]);
    __syncthreads();   // drains vmcnt -> staged data visible

    short8 af[4][2], bf[2][2];
#pragma unroll
    for (int kb = 0; kb < 2; kb++) {
#pragma unroll
      for (int i = 0; i < 4; i++)
        af[i][kb] = *(const short8*)&As[wm * 64 + i * 16 + li][kb * 32 + lg * 8];
#pragma unroll
      for (int j = 0; j < 2; j++)
        bf[j][kb] = *(const short8*)&Bs[wn * 32 + j * 16 + li][kb * 32 + lg * 8];
    }
#pragma unroll
    for (int kb = 0; kb < 2; kb++)
#pragma unroll
      for (int i = 0; i < 4; i++)
#pragma unroll
        for (int j = 0; j < 2; j++)
          acc[i][j] = mfma16(af[i][kb], bf[j][kb], acc[i][j]);
    __syncthreads();   // safe to restage next tile
  }

  // epilogue: C/D layout col=lane&15, row=(lane>>4)*4+reg
#pragma unroll
  for (int j = 0; j < 2; j++) {
    int col = bn * 64 + wn * 32 + j * 16 + li;
    float bv = bias[col];
#pragma unroll
    for (int i = 0; i < 4; i++) {
      int row0 = bm * 128 + wm * 64 + i * 16 + lg * 4;
#pragma unroll
      for (int r = 0; r < 4; r++)
        store_out(&C[(size_t)(row0 + r) * N + col], acc[i][j][r] + bv);
    }
  }
}

// ---------------- flash attention ----------------
// q,k,v,ctx layout: [B, S, H, DK] (i.e. [b*S+s][h*64+d], row stride 1024)
// LDS conflict fixes: Ks XOR-swizzled via pre-swizzled global source
// (global_load_lds dest must stay linear); Vt/Ps reg-staged -> pad to 72.
__global__ __launch_bounds__(256) void attn_fwd(
    const unsigned short* __restrict__ q, const unsigned short* __restrict__ k,
    const unsigned short* __restrict__ v, unsigned short* __restrict__ ctx) {
  __shared__ unsigned short Ks[64][64];      // [key][dk] swizzled 16B blocks
  __shared__ unsigned short Vt[64][72];      // [dk][key] padded
  __shared__ unsigned short Ps[4][16][72];   // per-wave P, padded

  const int tid = threadIdx.x;
  const int lane = tid & 63, wave = tid >> 6;
  const int li = lane & 15, lg = lane >> 4;
  const int qt = blockIdx.x, bh = blockIdx.y;
  const int b = bh >> 4, h = bh & 15;

  // Q fragments for this wave's 16 q-rows (A-operand: row=li, k=lg*8+j)
  const unsigned short* qg =
      q + (size_t)(b * S_ + qt * 64 + wave * 16 + li) * DM_ + h * DK_;
  short8 qf[2];
  qf[0] = *(const short8*)(qg + lg * 8);
  qf[1] = *(const short8*)(qg + 32 + lg * 8);

  const f32x4 zero4 = {0.f, 0.f, 0.f, 0.f};
  f32x4 po[4];
#pragma unroll
  for (int d = 0; d < 4; d++) po[d] = zero4;
  float m_i[4], l_i[4];
#pragma unroll
  for (int r = 0; r < 4; r++) { m_i[r] = -1e30f; l_i[r] = 0.f; }

  const float scale = 0.125f;  // 1/sqrt(64)

  // K staging: thread tid stages 16B at linear LDS offset tid*16
  // = row srow, 16B-block sc. Pre-swizzle the SOURCE column so that
  // physical block sc holds logical block sc ^ (srow&7).
  const int srow = tid >> 3;                   // 0..31
  const int sc = tid & 7;                      // 16B block index
  const int scs = (sc ^ (srow & 7)) * 8;       // swizzled source col (elems)
  const unsigned short* kg = k + (size_t)(b * S_) * DM_ + h * DK_;

  const int vkey = tid & 63;
  const int vd0 = (tid >> 6) * 16;
  const unsigned short* vg = v + (size_t)(b * S_) * DM_ + h * DK_;

  const int NT = S_ / 64;
  // prologue: issue V loads for tile 0
  short8 t0, t1;
  {
    const unsigned short* vp = vg + (size_t)vkey * DM_ + vd0;
    t0 = *(const short8*)(vp);
    t1 = *(const short8*)(vp + 8);
  }

  for (int kt = 0; kt < NT; kt++) {
    __syncthreads();  // prior tile's LDS reads complete before restage
    // stage K tile (async, swizzled source)
    const unsigned short* kgt = kg + (size_t)(kt * 64) * DM_;
    glds16(kgt + (size_t)srow * DM_ + scs, &Ks[srow][sc * 8]);
    glds16(kgt + (size_t)(32 + srow) * DM_ + scs, &Ks[32 + srow][sc * 8]);
    // write V tile (transposed) from regs loaded last iteration
#pragma unroll
    for (int j = 0; j < 8; j++) Vt[vd0 + j][vkey] = (unsigned short)t0[j];
#pragma unroll
    for (int j = 0; j < 8; j++) Vt[vd0 + 8 + j][vkey] = (unsigned short)t1[j];
    __syncthreads();  // glds drains at barrier; Vt visible

    // T14: issue NEXT tile's V loads now; latency hides under compute
    if (kt + 1 < NT) {
      const unsigned short* vp = vg + (size_t)((kt + 1) * 64 + vkey) * DM_ + vd0;
      t0 = *(const short8*)(vp);
      t1 = *(const short8*)(vp + 8);
    }

    // S = Q K^T  (16 rows x 64 keys per wave); swizzled Ks reads
    f32x4 sacc[4];
#pragma unroll
    for (int cb = 0; cb < 4; cb++) sacc[cb] = zero4;
#pragma unroll
    for (int cb = 0; cb < 4; cb++)
#pragma unroll
      for (int kb = 0; kb < 2; kb++) {
        short8 kf = *(const short8*)
            &Ks[cb * 16 + li][((kb * 4 + lg) ^ (li & 7)) * 8];
        sacc[cb] = mfma16(qf[kb], kf, sacc[cb]);
      }

    // online softmax (reg r -> row lg*4+r; row lives across 16-lane group)
    float p[4][4];
#pragma unroll
    for (int r = 0; r < 4; r++) {
      float rm = fmaxf(fmaxf(sacc[0][r], sacc[1][r]),
                       fmaxf(sacc[2][r], sacc[3][r]));
      rm = fmaxf(rm, __shfl_xor(rm, 1));
      rm = fmaxf(rm, __shfl_xor(rm, 2));
      rm = fmaxf(rm, __shfl_xor(rm, 4));
      rm = fmaxf(rm, __shfl_xor(rm, 8));
      float mnew = fmaxf(m_i[r], rm * scale);
      float alpha = __expf(m_i[r] - mnew);
      float rs = 0.f;
#pragma unroll
      for (int cb = 0; cb < 4; cb++) {
        float pv = __expf(sacc[cb][r] * scale - mnew);
        p[cb][r] = pv;
        rs += pv;
      }
      rs += __shfl_xor(rs, 1);
      rs += __shfl_xor(rs, 2);
      rs += __shfl_xor(rs, 4);
      rs += __shfl_xor(rs, 8);
      l_i[r] = l_i[r] * alpha + rs;
      m_i[r] = mnew;
#pragma unroll
      for (int d = 0; d < 4; d++) po[d][r] = po[d][r] * alpha;
    }

    // P (C-layout) -> LDS -> A-frag layout (per-wave buffer, no barrier)
#pragma unroll
    for (int cb = 0; cb < 4; cb++)
#pragma unroll
      for (int r = 0; r < 4; r++)
        Ps[wave][lg * 4 + r][cb * 16 + li] = f2bf(p[cb][r]);

    short8 pf0 = *(const short8*)&Ps[wave][li][lg * 8];
    short8 pf1 = *(const short8*)&Ps[wave][li][32 + lg * 8];

    // ctx += P @ V
#pragma unroll
    for (int d = 0; d < 4; d++) {
      short8 vf0 = *(const short8*)&Vt[d * 16 + li][lg * 8];
      short8 vf1 = *(const short8*)&Vt[d * 16 + li][32 + lg * 8];
      po[d] = mfma16(pf0, vf0, po[d]);
      po[d] = mfma16(pf1, vf1, po[d]);
    }
  }

  // epilogue: divide by l, store bf16 ctx in [B,S,H,DK]
  unsigned short* cg =
      ctx + (size_t)(b * S_ + qt * 64 + wave * 16) * DM_ + h * DK_;
#pragma unroll
  for (int d = 0; d < 4; d++)
#pragma unroll
    for (int r = 0; r < 4; r++) {
      int row = lg * 4 + r;
      cg[(size_t)row * DM_ + d * 16 + li] = f2bf(po[d][r] / l_i[r]);
    }
}

// ---------------- launch ----------------
extern "C" void kernel_launch(void* const* d_in, const int* in_sizes, int n_in,
                              void* d_out, int out_size, void* d_ws, size_t ws_size,
                              hipStream_t stream) {
  const float* Q  = (const float*)d_in[0];
  const float* Kx = (const float*)d_in[1];
  const float* V  = (const float*)d_in[2];
  const float* Wq = (const float*)d_in[3];
  const float* bq = (const float*)d_in[4];
  const float* Wk = (const float*)d_in[5];
  const float* bk = (const float*)d_in[6];
  const float* Wv = (const float*)d_in[7];
  const float* bv = (const float*)d_in[8];
  const float* Wo = (const float*)d_in[9];
  const float* bo = (const float*)d_in[10];
  float* out = (float*)d_out;

  char* ws = (char*)d_ws;
  const size_t MB = 1ull << 20;
  unsigned short* Qb  = (unsigned short*)(ws + 0 * MB);
  unsigned short* Kb  = (unsigned short*)(ws + 8 * MB);
  unsigned short* Vb  = (unsigned short*)(ws + 16 * MB);
  unsigned short* Wqb = (unsigned short*)(ws + 24 * MB);
  unsigned short* Wkb = (unsigned short*)(ws + 26 * MB);
  unsigned short* Wvb = (unsigned short*)(ws + 28 * MB);
  unsigned short* Wob = (unsigned short*)(ws + 30 * MB);
  unsigned short* qp  = (unsigned short*)(ws + 32 * MB);
  unsigned short* kp  = (unsigned short*)(ws + 40 * MB);
  unsigned short* vp  = (unsigned short*)(ws + 48 * MB);
  unsigned short* cx  = (unsigned short*)(ws + 56 * MB);  // 64 MB total

  const int nAct = B_ * S_ * DM_;  // 4194304
  const int nW = DM_ * DM_;        // 1048576

  cvt_f32_bf16<<<nAct / 4 / 256, 256, 0, stream>>>(Q, Qb, nAct / 4);
  cvt_f32_bf16<<<nAct / 4 / 256, 256, 0, stream>>>(Kx, Kb, nAct / 4);
  cvt_f32_bf16<<<nAct / 4 / 256, 256, 0, stream>>>(V, Vb, nAct / 4);
  cvt_f32_bf16<<<nW / 4 / 256, 256, 0, stream>>>(Wq, Wqb, nW / 4);
  cvt_f32_bf16<<<nW / 4 / 256, 256, 0, stream>>>(Wk, Wkb, nW / 4);
  cvt_f32_bf16<<<nW / 4 / 256, 256, 0, stream>>>(Wv, Wvb, nW / 4);
  cvt_f32_bf16<<<nW / 4 / 256, 256, 0, stream>>>(Wo, Wob, nW / 4);

  dim3 gg(32, 16);  // M/128 x N/64
  gemm_bt<unsigned short><<<gg, 256, 0, stream>>>(Qb, Wqb, bq, qp, 4096, 1024, 1024);
  gemm_bt<unsigned short><<<gg, 256, 0, stream>>>(Kb, Wkb, bk, kp, 4096, 1024, 1024);
  gemm_bt<unsigned short><<<gg, 256, 0, stream>>>(Vb, Wvb, bv, vp, 4096, 1024, 1024);

  attn_fwd<<<dim3(32, 32), 256, 0, stream>>>(qp, kp, vp, cx);

  gemm_bt<float><<<gg, 256, 0, stream>>>(cx, Wob, bo, out, 4096, 1024, 1024);
}

// Round 4
// 189.817 us; speedup vs baseline: 1.4980x; 1.2420x over previous
//
#include <hip/hip_runtime.h>
#include <hip/hip_bf16.h>
#include <cstdint>
#include <cstddef>
#include <cmath>

typedef __attribute__((ext_vector_type(8))) short short8;
typedef __attribute__((ext_vector_type(4))) short short4_t;
typedef __attribute__((ext_vector_type(4))) float f32x4;

constexpr int B_ = 2, S_ = 2048, H_ = 16, DK_ = 64, DM_ = 1024;

__device__ inline unsigned short f2bf(float x) {
  union { float f; unsigned u; } c; c.f = x;
  unsigned r = c.u + 0x7FFF + ((c.u >> 16) & 1);
  return (unsigned short)(r >> 16);
}

// native 2^x
__device__ inline float ex2(float x) {
#if __has_builtin(__builtin_amdgcn_exp2f)
  return __builtin_amdgcn_exp2f(x);
#else
  return exp2f(x);
#endif
}

// packed f32x2 -> bf16x2 (RNE), single HW op
__device__ inline unsigned pkbf(float lo, float hi) {
  unsigned u;
  asm("v_cvt_pk_bf16_f32 %0, %1, %2" : "=v"(u) : "v"(lo), "v"(hi));
  return u;
}

__device__ inline f32x4 mfma16(short8 a, short8 b, f32x4 c) {
  return __builtin_amdgcn_mfma_f32_16x16x32_bf16(a, b, c, 0, 0, 0);
}

// async global->LDS, 16B per lane; LDS dest must be linear (base + lane*16)
__device__ inline void glds16(const unsigned short* g, unsigned short* l) {
  __builtin_amdgcn_global_load_lds(
      (const __attribute__((address_space(1))) unsigned int*)g,
      (__attribute__((address_space(3))) unsigned int*)l, 16, 0, 0);
}

// ---------------- fused f32 -> bf16 convert for all 7 tensors ------------
__global__ __launch_bounds__(256) void cvt_all(
    const float* __restrict__ Q, const float* __restrict__ K,
    const float* __restrict__ V, const float* __restrict__ Wq,
    const float* __restrict__ Wk, const float* __restrict__ Wv,
    const float* __restrict__ Wo, unsigned short* __restrict__ Qb,
    unsigned short* __restrict__ Kb, unsigned short* __restrict__ Vb,
    unsigned short* __restrict__ Wqb, unsigned short* __restrict__ Wkb,
    unsigned short* __restrict__ Wvb, unsigned short* __restrict__ Wob) {
  int bid = blockIdx.x;
  const float* in; unsigned short* out; int off;
  if (bid < 4096)       { in = Q;  out = Qb;  off = bid; }
  else if (bid < 8192)  { in = K;  out = Kb;  off = bid - 4096; }
  else if (bid < 12288) { in = V;  out = Vb;  off = bid - 8192; }
  else if (bid < 13312) { in = Wq; out = Wqb; off = bid - 12288; }
  else if (bid < 14336) { in = Wk; out = Wkb; off = bid - 13312; }
  else if (bid < 15360) { in = Wv; out = Wvb; off = bid - 14336; }
  else                  { in = Wo; out = Wob; off = bid - 15360; }
  int i = off * 256 + threadIdx.x;
  float4 f = ((const float4*)in)[i];
  uint2 o;
  o.x = pkbf(f.x, f.y);
  o.y = pkbf(f.z, f.w);
  ((uint2*)out)[i] = o;
}

// ---------------- bf16 GEMM body: C = (A * Bw^T + bias) * cscale ----------
// fixed 4096x1024x1024, 128x64 tile, 4 waves (2x2, 64x32 each)
__device__ inline void store_out(float* p, float v) { *p = v; }
__device__ inline void store_out(unsigned short* p, float v) { *p = f2bf(v); }

template <typename OUT_T>
__device__ inline void gemm_body(const unsigned short* __restrict__ A,
                                 const unsigned short* __restrict__ Bw,
                                 const float* __restrict__ bias,
                                 OUT_T* __restrict__ C, float cscale,
                                 int bm, int bn) {
  constexpr int Kd = 1024, Nd = 1024;
  __shared__ unsigned short As[128][64];  // 16 KB
  __shared__ unsigned short Bs[64][64];   // 8 KB

  const int tid = threadIdx.x;
  const int lane = tid & 63, wave = tid >> 6;
  const int li = lane & 15, lg = lane >> 4;
  const int wm = wave >> 1, wn = wave & 1;

  const f32x4 zero4 = {0.f, 0.f, 0.f, 0.f};
  f32x4 acc[4][2];
#pragma unroll
  for (int i = 0; i < 4; i++)
#pragma unroll
    for (int j = 0; j < 2; j++) acc[i][j] = zero4;

  const int stg_row = tid >> 3;
  const int stg_col = (tid & 7) * 8;
  const unsigned short* Ag = A + (size_t)(bm * 128 + stg_row) * Kd + stg_col;
  const unsigned short* Bg = Bw + (size_t)(bn * 64 + stg_row) * Kd + stg_col;

  for (int kt = 0; kt < Kd; kt += 64) {
#pragma unroll
    for (int i = 0; i < 4; i++)
      glds16(Ag + (size_t)(i * 32) * Kd + kt, &As[i * 32 + stg_row][stg_col]);
#pragma unroll
    for (int i = 0; i < 2; i++)
      glds16(Bg + (size_t)(i * 32) * Kd + kt, &Bs[i * 32 + stg_row][stg_col]);
    __syncthreads();

    short8 af[4][2], bf[2][2];
#pragma unroll
    for (int kb = 0; kb < 2; kb++) {
#pragma unroll
      for (int i = 0; i < 4; i++)
        af[i][kb] = *(const short8*)&As[wm * 64 + i * 16 + li][kb * 32 + lg * 8];
#pragma unroll
      for (int j = 0; j < 2; j++)
        bf[j][kb] = *(const short8*)&Bs[wn * 32 + j * 16 + li][kb * 32 + lg * 8];
    }
#pragma unroll
    for (int kb = 0; kb < 2; kb++)
#pragma unroll
      for (int i = 0; i < 4; i++)
#pragma unroll
        for (int j = 0; j < 2; j++)
          acc[i][j] = mfma16(af[i][kb], bf[j][kb], acc[i][j]);
    __syncthreads();
  }

#pragma unroll
  for (int j = 0; j < 2; j++) {
    int col = bn * 64 + wn * 32 + j * 16 + li;
    float bv = bias[col];
#pragma unroll
    for (int i = 0; i < 4; i++) {
      int row0 = bm * 128 + wm * 64 + i * 16 + lg * 4;
#pragma unroll
      for (int r = 0; r < 4; r++)
        store_out(&C[(size_t)(row0 + r) * Nd + col], (acc[i][j][r] + bv) * cscale);
    }
  }
}

__global__ __launch_bounds__(256) void gemm_qkv(
    const unsigned short* __restrict__ Aq, const unsigned short* __restrict__ Ak,
    const unsigned short* __restrict__ Av, const unsigned short* __restrict__ Bq,
    const unsigned short* __restrict__ Bk, const unsigned short* __restrict__ Bv,
    const float* __restrict__ bq, const float* __restrict__ bk,
    const float* __restrict__ bv, unsigned short* __restrict__ Cq,
    unsigned short* __restrict__ Ck, unsigned short* __restrict__ Cv,
    float qscale) {
  int z = blockIdx.z;
  const unsigned short* A = z == 0 ? Aq : z == 1 ? Ak : Av;
  const unsigned short* Bw = z == 0 ? Bq : z == 1 ? Bk : Bv;
  const float* bi = z == 0 ? bq : z == 1 ? bk : bv;
  unsigned short* C = z == 0 ? Cq : z == 1 ? Ck : Cv;
  gemm_body(A, Bw, bi, C, z == 0 ? qscale : 1.0f, blockIdx.x, blockIdx.y);
}

__global__ __launch_bounds__(256) void gemm_out(
    const unsigned short* __restrict__ A, const unsigned short* __restrict__ Bw,
    const float* __restrict__ bias, float* __restrict__ C) {
  gemm_body(A, Bw, bias, C, 1.0f, blockIdx.x, blockIdx.y);
}

// ---------------- flash attention ----------------
// q pre-scaled by (1/8)*log2(e) in GEMM epilogue -> softmax is pure exp2.
// K double-buffered in LDS via raw barriers + manual waitcnt; prefetched
// loads stay in flight across the compute phase (drained at NEXT tile's B1,
// own-vmcnt BEFORE s_barrier so all waves' staging is visible after it).
// V reg-carried (T14). Defer-max (T13, THR=8).
__global__ __launch_bounds__(256) void attn_fwd(
    const unsigned short* __restrict__ q, const unsigned short* __restrict__ k,
    const unsigned short* __restrict__ v, unsigned short* __restrict__ ctx) {
  __shared__ unsigned short Ks[2][64][64];   // 16 KB, XOR-swizzled 16B blocks
  __shared__ unsigned short Vt[64][72];      // [dk][key] padded, 9 KB
  __shared__ unsigned short Ps[4][16][76];   // per-wave P, padded, 9.5 KB

  const int tid = threadIdx.x;
  const int lane = tid & 63, wave = tid >> 6;
  const int li = lane & 15, lg = lane >> 4;
  const int qt = blockIdx.x, bh = blockIdx.y;
  const int b = bh >> 4, h = bh & 15;

  const unsigned short* qg =
      q + (size_t)(b * S_ + qt * 64 + wave * 16 + li) * DM_ + h * DK_;
  short8 qf[2];
  qf[0] = *(const short8*)(qg + lg * 8);
  qf[1] = *(const short8*)(qg + 32 + lg * 8);

  const f32x4 zero4 = {0.f, 0.f, 0.f, 0.f};
  f32x4 po[4];
#pragma unroll
  for (int d = 0; d < 4; d++) po[d] = zero4;
  float m_i[4], l_i[4];
#pragma unroll
  for (int r = 0; r < 4; r++) { m_i[r] = -1e30f; l_i[r] = 0.f; }

  // K staging: linear LDS dest, XOR-swizzled global source (rule #21)
  const int srow = tid >> 3;                 // 0..31
  const int sc = tid & 7;                    // 16B block
  const int scs = (sc ^ (srow & 7)) * 8;     // swizzled source col
  const unsigned short* kg = k + (size_t)(b * S_) * DM_ + h * DK_;

  // V staging: 2 keys x 8 d's per thread, packed u32 writes
  const int vkey2 = (tid & 31) * 2;
  const int vd0 = (tid >> 5) * 8;
  const unsigned short* vg = v + (size_t)(b * S_) * DM_ + h * DK_;

  const int NT = S_ / 64;

  // prologue: stage K(0), load V(0) to regs
  glds16(kg + (size_t)srow * DM_ + scs, &Ks[0][srow][sc * 8]);
  glds16(kg + (size_t)(32 + srow) * DM_ + scs, &Ks[0][32 + srow][sc * 8]);
  short8 t0, t1;
  {
    const unsigned short* vp = vg + (size_t)vkey2 * DM_ + vd0;
    t0 = *(const short8*)(vp);
    t1 = *(const short8*)(vp + DM_);
  }

  for (int kt = 0; kt < NT; kt++) {
    const int buf = kt & 1;
    // B1: drain OWN staging loads first, then barrier -> after the barrier
    // every wave's K(kt) glds and V(kt) reg-loads are complete & visible.
    asm volatile("s_waitcnt vmcnt(0)" ::: "memory");
    __builtin_amdgcn_sched_barrier(0);
    __builtin_amdgcn_s_barrier();
    __builtin_amdgcn_sched_barrier(0);

    // write V(kt) transposed, packed u32 (bank = key -> conflict-free)
#pragma unroll
    for (int j = 0; j < 8; j++) {
      unsigned w = (unsigned)(unsigned short)t0[j] |
                   ((unsigned)(unsigned short)t1[j] << 16);
      *(unsigned*)&Vt[vd0 + j][vkey2] = w;
    }

    // prefetch next tile: K glds into other buffer, V into regs (in flight
    // across the whole compute phase; drained at next iteration's B1)
    if (kt + 1 < NT) {
      const unsigned short* kgt = kg + (size_t)((kt + 1) * 64) * DM_;
      glds16(kgt + (size_t)srow * DM_ + scs, &Ks[buf ^ 1][srow][sc * 8]);
      glds16(kgt + (size_t)(32 + srow) * DM_ + scs, &Ks[buf ^ 1][32 + srow][sc * 8]);
      const unsigned short* vp = vg + (size_t)((kt + 1) * 64 + vkey2) * DM_ + vd0;
      t0 = *(const short8*)(vp);
      t1 = *(const short8*)(vp + DM_);
    }

    // B2: Vt ds_writes landed (own lgkmcnt; all waves at barrier)
    asm volatile("s_waitcnt lgkmcnt(0)" ::: "memory");
    __builtin_amdgcn_sched_barrier(0);
    __builtin_amdgcn_s_barrier();
    __builtin_amdgcn_sched_barrier(0);

    // S = Q K^T (pre-scaled -> exp2 domain)
    f32x4 sacc[4];
#pragma unroll
    for (int cb = 0; cb < 4; cb++) sacc[cb] = zero4;
#pragma unroll
    for (int cb = 0; cb < 4; cb++)
#pragma unroll
      for (int kb = 0; kb < 2; kb++) {
        short8 kf = *(const short8*)
            &Ks[buf][cb * 16 + li][((kb * 4 + lg) ^ (li & 7)) * 8];
        sacc[cb] = mfma16(qf[kb], kf, sacc[cb]);
      }

    // online softmax, defer-max
    float rm[4];
#pragma unroll
    for (int r = 0; r < 4; r++) {
      float x = fmaxf(fmaxf(sacc[0][r], sacc[1][r]),
                      fmaxf(sacc[2][r], sacc[3][r]));
      x = fmaxf(x, __shfl_xor(x, 1));
      x = fmaxf(x, __shfl_xor(x, 2));
      x = fmaxf(x, __shfl_xor(x, 4));
      x = fmaxf(x, __shfl_xor(x, 8));
      rm[r] = x;
    }
    float need = fmaxf(fmaxf(rm[0] - m_i[0], rm[1] - m_i[1]),
                       fmaxf(rm[2] - m_i[2], rm[3] - m_i[3]));
    if (!__all(need <= 8.0f)) {
#pragma unroll
      for (int r = 0; r < 4; r++) {
        float mn = fmaxf(m_i[r], rm[r]);
        float al = ex2(m_i[r] - mn);
        m_i[r] = mn;
        l_i[r] *= al;
#pragma unroll
        for (int d = 0; d < 4; d++) po[d][r] *= al;
      }
    }
#pragma unroll
    for (int r = 0; r < 4; r++) {
      float p0 = ex2(sacc[0][r] - m_i[r]);
      float p1 = ex2(sacc[1][r] - m_i[r]);
      float p2 = ex2(sacc[2][r] - m_i[r]);
      float p3 = ex2(sacc[3][r] - m_i[r]);
      float rs = (p0 + p1) + (p2 + p3);
      rs += __shfl_xor(rs, 1);
      rs += __shfl_xor(rs, 2);
      rs += __shfl_xor(rs, 4);
      rs += __shfl_xor(rs, 8);
      l_i[r] += rs;
      unsigned ua = pkbf(p0, p1), ub = pkbf(p2, p3);
      Ps[wave][lg * 4 + r][li] = (unsigned short)ua;
      Ps[wave][lg * 4 + r][16 + li] = (unsigned short)(ua >> 16);
      Ps[wave][lg * 4 + r][32 + li] = (unsigned short)ub;
      Ps[wave][lg * 4 + r][48 + li] = (unsigned short)(ub >> 16);
    }

    short8 pf0 = *(const short8*)&Ps[wave][li][lg * 8];
    short8 pf1 = *(const short8*)&Ps[wave][li][32 + lg * 8];

    // ctx += P @ V
#pragma unroll
    for (int d = 0; d < 4; d++) {
      short8 vf0 = *(const short8*)&Vt[d * 16 + li][lg * 8];
      short8 vf1 = *(const short8*)&Vt[d * 16 + li][32 + lg * 8];
      po[d] = mfma16(pf0, vf0, po[d]);
      po[d] = mfma16(pf1, vf1, po[d]);
    }
  }

  // epilogue
  float rl[4];
#pragma unroll
  for (int r = 0; r < 4; r++) rl[r] = 1.0f / l_i[r];
  unsigned short* cg =
      ctx + (size_t)(b * S_ + qt * 64 + wave * 16) * DM_ + h * DK_;
#pragma unroll
  for (int d = 0; d < 4; d++)
#pragma unroll
    for (int r = 0; r < 4; r += 2) {
      unsigned u = pkbf(po[d][r] * rl[r], po[d][r + 1] * rl[r + 1]);
      cg[(size_t)(lg * 4 + r) * DM_ + d * 16 + li] = (unsigned short)u;
      cg[(size_t)(lg * 4 + r + 1) * DM_ + d * 16 + li] = (unsigned short)(u >> 16);
    }
}

// ---------------- launch ----------------
extern "C" void kernel_launch(void* const* d_in, const int* in_sizes, int n_in,
                              void* d_out, int out_size, void* d_ws, size_t ws_size,
                              hipStream_t stream) {
  const float* Q  = (const float*)d_in[0];
  const float* Kx = (const float*)d_in[1];
  const float* V  = (const float*)d_in[2];
  const float* Wq = (const float*)d_in[3];
  const float* bq = (const float*)d_in[4];
  const float* Wk = (const float*)d_in[5];
  const float* bk = (const float*)d_in[6];
  const float* Wv = (const float*)d_in[7];
  const float* bv = (const float*)d_in[8];
  const float* Wo = (const float*)d_in[9];
  const float* bo = (const float*)d_in[10];
  float* out = (float*)d_out;

  char* ws = (char*)d_ws;
  const size_t MB = 1ull << 20;
  unsigned short* Qb  = (unsigned short*)(ws + 0 * MB);
  unsigned short* Kb  = (unsigned short*)(ws + 8 * MB);
  unsigned short* Vb  = (unsigned short*)(ws + 16 * MB);
  unsigned short* Wqb = (unsigned short*)(ws + 24 * MB);
  unsigned short* Wkb = (unsigned short*)(ws + 26 * MB);
  unsigned short* Wvb = (unsigned short*)(ws + 28 * MB);
  unsigned short* Wob = (unsigned short*)(ws + 30 * MB);
  unsigned short* qp  = (unsigned short*)(ws + 32 * MB);
  unsigned short* kp  = (unsigned short*)(ws + 40 * MB);
  unsigned short* vp  = (unsigned short*)(ws + 48 * MB);
  unsigned short* cx  = (unsigned short*)(ws + 56 * MB);  // 64 MB total

  cvt_all<<<16384, 256, 0, stream>>>(Q, Kx, V, Wq, Wk, Wv, Wo,
                                     Qb, Kb, Vb, Wqb, Wkb, Wvb, Wob);

  // Q projection pre-scaled by (1/sqrt(dk)) * log2(e)
  gemm_qkv<<<dim3(32, 16, 3), 256, 0, stream>>>(
      Qb, Kb, Vb, Wqb, Wkb, Wvb, bq, bk, bv, qp, kp, vp, 0.18033688f);

  attn_fwd<<<dim3(32, 32), 256, 0, stream>>>(qp, kp, vp, cx);

  gemm_out<<<dim3(32, 16), 256, 0, stream>>>(cx, Wob, bo, out);
}

// Round 5
// 152.033 us; speedup vs baseline: 1.8703x; 1.2485x over previous
//
#include <hip/hip_runtime.h>
#include <hip/hip_bf16.h>
#include <cstdint>
#include <cstddef>
#include <cmath>

typedef __attribute__((ext_vector_type(8))) short short8;
typedef __attribute__((ext_vector_type(4))) short short4_t;
typedef __attribute__((ext_vector_type(4))) float f32x4;

constexpr int B_ = 2, S_ = 2048, H_ = 16, DK_ = 64, DM_ = 1024;

__device__ inline unsigned short f2bf(float x) {
  union { float f; unsigned u; } c; c.f = x;
  unsigned r = c.u + 0x7FFF + ((c.u >> 16) & 1);
  return (unsigned short)(r >> 16);
}

// native 2^x
__device__ inline float ex2(float x) {
#if __has_builtin(__builtin_amdgcn_exp2f)
  return __builtin_amdgcn_exp2f(x);
#else
  return exp2f(x);
#endif
}

// packed f32x2 -> bf16x2 (RNE), single HW op
__device__ inline unsigned pkbf(float lo, float hi) {
  unsigned u;
  asm("v_cvt_pk_bf16_f32 %0, %1, %2" : "=v"(u) : "v"(lo), "v"(hi));
  return u;
}

__device__ inline f32x4 mfma16(short8 a, short8 b, f32x4 c) {
  return __builtin_amdgcn_mfma_f32_16x16x32_bf16(a, b, c, 0, 0, 0);
}

// async global->LDS, 16B per lane; LDS dest must be linear (base + lane*16)
__device__ inline void glds16(const unsigned short* g, unsigned short* l) {
  __builtin_amdgcn_global_load_lds(
      (const __attribute__((address_space(1))) unsigned int*)g,
      (__attribute__((address_space(3))) unsigned int*)l, 16, 0, 0);
}

// ---------------- fused f32 -> bf16 convert for all 7 tensors ------------
__global__ __launch_bounds__(256) void cvt_all(
    const float* __restrict__ Q, const float* __restrict__ K,
    const float* __restrict__ V, const float* __restrict__ Wq,
    const float* __restrict__ Wk, const float* __restrict__ Wv,
    const float* __restrict__ Wo, unsigned short* __restrict__ Qb,
    unsigned short* __restrict__ Kb, unsigned short* __restrict__ Vb,
    unsigned short* __restrict__ Wqb, unsigned short* __restrict__ Wkb,
    unsigned short* __restrict__ Wvb, unsigned short* __restrict__ Wob) {
  int bid = blockIdx.x;
  const float* in; unsigned short* out; int off;
  if (bid < 4096)       { in = Q;  out = Qb;  off = bid; }
  else if (bid < 8192)  { in = K;  out = Kb;  off = bid - 4096; }
  else if (bid < 12288) { in = V;  out = Vb;  off = bid - 8192; }
  else if (bid < 13312) { in = Wq; out = Wqb; off = bid - 12288; }
  else if (bid < 14336) { in = Wk; out = Wkb; off = bid - 13312; }
  else if (bid < 15360) { in = Wv; out = Wvb; off = bid - 14336; }
  else                  { in = Wo; out = Wob; off = bid - 15360; }
  int i = off * 256 + threadIdx.x;
  float4 f = ((const float4*)in)[i];
  uint2 o;
  o.x = pkbf(f.x, f.y);
  o.y = pkbf(f.z, f.w);
  ((uint2*)out)[i] = o;
}

// ---------------- bf16 GEMM body: C = (A * Bw^T + bias) * cscale ----------
// fixed 4096x1024x1024, 128x64 tile, 4 waves (2x2, 64x32 each)
__device__ inline void store_out(float* p, float v) { *p = v; }
__device__ inline void store_out(unsigned short* p, float v) { *p = f2bf(v); }

template <typename OUT_T>
__device__ inline void gemm_body(const unsigned short* __restrict__ A,
                                 const unsigned short* __restrict__ Bw,
                                 const float* __restrict__ bias,
                                 OUT_T* __restrict__ C, float cscale,
                                 int bm, int bn) {
  constexpr int Kd = 1024, Nd = 1024;
  __shared__ unsigned short As[128][64];  // 16 KB
  __shared__ unsigned short Bs[64][64];   // 8 KB

  const int tid = threadIdx.x;
  const int lane = tid & 63, wave = tid >> 6;
  const int li = lane & 15, lg = lane >> 4;
  const int wm = wave >> 1, wn = wave & 1;

  const f32x4 zero4 = {0.f, 0.f, 0.f, 0.f};
  f32x4 acc[4][2];
#pragma unroll
  for (int i = 0; i < 4; i++)
#pragma unroll
    for (int j = 0; j < 2; j++) acc[i][j] = zero4;

  const int stg_row = tid >> 3;
  const int stg_col = (tid & 7) * 8;
  const unsigned short* Ag = A + (size_t)(bm * 128 + stg_row) * Kd + stg_col;
  const unsigned short* Bg = Bw + (size_t)(bn * 64 + stg_row) * Kd + stg_col;

  for (int kt = 0; kt < Kd; kt += 64) {
#pragma unroll
    for (int i = 0; i < 4; i++)
      glds16(Ag + (size_t)(i * 32) * Kd + kt, &As[i * 32 + stg_row][stg_col]);
#pragma unroll
    for (int i = 0; i < 2; i++)
      glds16(Bg + (size_t)(i * 32) * Kd + kt, &Bs[i * 32 + stg_row][stg_col]);
    __syncthreads();

    short8 af[4][2], bf[2][2];
#pragma unroll
    for (int kb = 0; kb < 2; kb++) {
#pragma unroll
      for (int i = 0; i < 4; i++)
        af[i][kb] = *(const short8*)&As[wm * 64 + i * 16 + li][kb * 32 + lg * 8];
#pragma unroll
      for (int j = 0; j < 2; j++)
        bf[j][kb] = *(const short8*)&Bs[wn * 32 + j * 16 + li][kb * 32 + lg * 8];
    }
#pragma unroll
    for (int kb = 0; kb < 2; kb++)
#pragma unroll
      for (int i = 0; i < 4; i++)
#pragma unroll
        for (int j = 0; j < 2; j++)
          acc[i][j] = mfma16(af[i][kb], bf[j][kb], acc[i][j]);
    __syncthreads();
  }

#pragma unroll
  for (int j = 0; j < 2; j++) {
    int col = bn * 64 + wn * 32 + j * 16 + li;
    float bv = bias[col];
#pragma unroll
    for (int i = 0; i < 4; i++) {
      int row0 = bm * 128 + wm * 64 + i * 16 + lg * 4;
#pragma unroll
      for (int r = 0; r < 4; r++)
        store_out(&C[(size_t)(row0 + r) * Nd + col], (acc[i][j][r] + bv) * cscale);
    }
  }
}

// 1D grid 1536: xcd=n&7 owns bm in [xcd*4, xcd*4+4) for each z
// -> per-XCD L2 footprint: 4 A-panels (1MB) + B (2MB) = 3MB < 4MB
__global__ __launch_bounds__(256) void gemm_qkv(
    const unsigned short* __restrict__ Aq, const unsigned short* __restrict__ Ak,
    const unsigned short* __restrict__ Av, const unsigned short* __restrict__ Bq,
    const unsigned short* __restrict__ Bk, const unsigned short* __restrict__ Bv,
    const float* __restrict__ bq, const float* __restrict__ bk,
    const float* __restrict__ bv, unsigned short* __restrict__ Cq,
    unsigned short* __restrict__ Ck, unsigned short* __restrict__ Cv,
    float qscale) {
  const int n = blockIdx.x;
  const int xcd = n & 7, m = n >> 3;
  const int z = m >> 6, idx = m & 63;
  const int bm = xcd * 4 + (idx >> 4), bn = idx & 15;
  const unsigned short* A = z == 0 ? Aq : z == 1 ? Ak : Av;
  const unsigned short* Bw = z == 0 ? Bq : z == 1 ? Bk : Bv;
  const float* bi = z == 0 ? bq : z == 1 ? bk : bv;
  unsigned short* C = z == 0 ? Cq : z == 1 ? Ck : Cv;
  gemm_body(A, Bw, bi, C, z == 0 ? qscale : 1.0f, bm, bn);
}

__global__ __launch_bounds__(256) void gemm_out(
    const unsigned short* __restrict__ A, const unsigned short* __restrict__ Bw,
    const float* __restrict__ bias, float* __restrict__ C) {
  const int n = blockIdx.x;
  const int xcd = n & 7, m = n >> 3;
  const int bm = xcd * 4 + (m >> 4), bn = m & 15;
  gemm_body(A, Bw, bias, C, 1.0f, bm, bn);
}

// ---------------- flash attention (swapped-QK, in-lane softmax) ----------
// q pre-scaled by (1/8)*log2(e) -> softmax is pure exp2.
// S^T = mfma(K,Q): lane (li,lg) holds S[q=li][key=cb*16+4lg+r] -> row stats
// are in-lane trees + 2 shfls. PV swapped too: ctx^T = mfma(V^T, P^T).
// XCD swizzle: each XCD owns 4 bh pairs (2MB K/V -> L2-resident).
__global__ __launch_bounds__(256) void attn_fwd(
    const unsigned short* __restrict__ q, const unsigned short* __restrict__ k,
    const unsigned short* __restrict__ v, unsigned short* __restrict__ ctx) {
  __shared__ unsigned short Ks[2][64][64];   // 16 KB, XOR-swizzled 16B blocks
  __shared__ unsigned short Vt[64][72];      // [dk][key] padded, 9 KB
  __shared__ unsigned short Ps[4][16][72];   // per-wave P^T [q][key], 9 KB

  const int tid = threadIdx.x;
  const int lane = tid & 63, wave = tid >> 6;
  const int li = lane & 15, lg = lane >> 4;
  const int n = blockIdx.x;
  const int xcd = n & 7, m = n >> 3;
  const int bh = xcd * 4 + (m & 3);
  const int qt = m >> 2;
  const int b = bh >> 4, h = bh & 15;

  const unsigned short* qg =
      q + (size_t)(b * S_ + qt * 64 + wave * 16 + li) * DM_ + h * DK_;
  short8 qf[2];
  qf[0] = *(const short8*)(qg + lg * 8);
  qf[1] = *(const short8*)(qg + 32 + lg * 8);

  const f32x4 zero4 = {0.f, 0.f, 0.f, 0.f};
  f32x4 po[4];                       // po[db][r] = ctx[q=li][d=db*16+4lg+r]
#pragma unroll
  for (int d = 0; d < 4; d++) po[d] = zero4;
  float m_i = -1e30f, l_i = 0.f;     // per-lane scalars (row = li)

  // K staging: linear LDS dest, XOR-swizzled global source (rule #21)
  const int srow = tid >> 3;                 // 0..31
  const int sc = tid & 7;                    // 16B block
  const int scs = (sc ^ (srow & 7)) * 8;     // swizzled source col
  const unsigned short* kg = k + (size_t)(b * S_) * DM_ + h * DK_;

  // V staging: 2 keys x 8 d's per thread, packed u32 writes
  const int vkey2 = (tid & 31) * 2;
  const int vd0 = (tid >> 5) * 8;
  const unsigned short* vg = v + (size_t)(b * S_) * DM_ + h * DK_;

  const int NT = S_ / 64;

  // prologue: stage K(0), load V(0) to regs
  glds16(kg + (size_t)srow * DM_ + scs, &Ks[0][srow][sc * 8]);
  glds16(kg + (size_t)(32 + srow) * DM_ + scs, &Ks[0][32 + srow][sc * 8]);
  short8 t0, t1;
  {
    const unsigned short* vp = vg + (size_t)vkey2 * DM_ + vd0;
    t0 = *(const short8*)(vp);
    t1 = *(const short8*)(vp + DM_);
  }

  for (int kt = 0; kt < NT; kt++) {
    const int buf = kt & 1;
    // B1: drain OWN staging loads, then barrier -> all waves' K(kt)/V(kt) done
    asm volatile("s_waitcnt vmcnt(0)" ::: "memory");
    __builtin_amdgcn_sched_barrier(0);
    __builtin_amdgcn_s_barrier();
    __builtin_amdgcn_sched_barrier(0);

    // write V(kt) transposed, packed u32 (bank = key -> conflict-free)
#pragma unroll
    for (int j = 0; j < 8; j++) {
      unsigned w = (unsigned)(unsigned short)t0[j] |
                   ((unsigned)(unsigned short)t1[j] << 16);
      *(unsigned*)&Vt[vd0 + j][vkey2] = w;
    }

    // prefetch next tile (in flight across compute; drained at next B1)
    if (kt + 1 < NT) {
      const unsigned short* kgt = kg + (size_t)((kt + 1) * 64) * DM_;
      glds16(kgt + (size_t)srow * DM_ + scs, &Ks[buf ^ 1][srow][sc * 8]);
      glds16(kgt + (size_t)(32 + srow) * DM_ + scs, &Ks[buf ^ 1][32 + srow][sc * 8]);
      const unsigned short* vp = vg + (size_t)((kt + 1) * 64 + vkey2) * DM_ + vd0;
      t0 = *(const short8*)(vp);
      t1 = *(const short8*)(vp + DM_);
    }

    // B2: Vt ds_writes landed
    asm volatile("s_waitcnt lgkmcnt(0)" ::: "memory");
    __builtin_amdgcn_sched_barrier(0);
    __builtin_amdgcn_s_barrier();
    __builtin_amdgcn_sched_barrier(0);

    // S^T = K Q^T: sacc[cb][r] = S[q=li][key=cb*16+4lg+r] (exp2 domain)
    f32x4 sacc[4];
#pragma unroll
    for (int cb = 0; cb < 4; cb++) sacc[cb] = zero4;
#pragma unroll
    for (int cb = 0; cb < 4; cb++)
#pragma unroll
      for (int kb = 0; kb < 2; kb++) {
        short8 kf = *(const short8*)
            &Ks[buf][cb * 16 + li][((kb * 4 + lg) ^ (li & 7)) * 8];
        sacc[cb] = mfma16(kf, qf[kb], sacc[cb]);
      }

    // in-lane row max (16 values) + 2 shfls across lg groups
    float mx;
    {
      f32x4 t01, t23;
#pragma unroll
      for (int r = 0; r < 4; r++) {
        t01[r] = fmaxf(sacc[0][r], sacc[1][r]);
        t23[r] = fmaxf(sacc[2][r], sacc[3][r]);
      }
      float a = fmaxf(fmaxf(t01[0], t01[1]), fmaxf(t01[2], t01[3]));
      float c = fmaxf(fmaxf(t23[0], t23[1]), fmaxf(t23[2], t23[3]));
      mx = fmaxf(a, c);
    }
    mx = fmaxf(mx, __shfl_xor(mx, 16));
    mx = fmaxf(mx, __shfl_xor(mx, 32));

    // defer-max (T13): skip rescale while growth <= 8 (p bounded by 256)
    if (!__all(mx - m_i <= 8.0f)) {
      float mn = fmaxf(m_i, mx);
      float al = ex2(m_i - mn);
      m_i = mn;
      l_i *= al;
#pragma unroll
      for (int d = 0; d < 4; d++)
#pragma unroll
        for (int r = 0; r < 4; r++) po[d][r] *= al;
    }

    // p = exp2(s - m); in-lane sum + 2 shfls; stage P^T to LDS
    float p[4][4];
#pragma unroll
    for (int cb = 0; cb < 4; cb++)
#pragma unroll
      for (int r = 0; r < 4; r++) p[cb][r] = ex2(sacc[cb][r] - m_i);
    float s0 = (p[0][0] + p[0][1]) + (p[0][2] + p[0][3]);
    float s1 = (p[1][0] + p[1][1]) + (p[1][2] + p[1][3]);
    float s2 = (p[2][0] + p[2][1]) + (p[2][2] + p[2][3]);
    float s3 = (p[3][0] + p[3][1]) + (p[3][2] + p[3][3]);
    float sum = (s0 + s1) + (s2 + s3);
    sum += __shfl_xor(sum, 16);
    sum += __shfl_xor(sum, 32);
    l_i += sum;

#pragma unroll
    for (int cb = 0; cb < 4; cb++) {
      uint2 w;
      w.x = pkbf(p[cb][0], p[cb][1]);
      w.y = pkbf(p[cb][2], p[cb][3]);
      *(uint2*)&Ps[wave][li][cb * 16 + lg * 4] = w;  // keys cb*16+4lg..+3
    }

    // PV swapped: ctx^T = V^T P^T; B-frag = P^T[q=li][key=lg*8+j]
    short8 pf0 = *(const short8*)&Ps[wave][li][lg * 8];
    short8 pf1 = *(const short8*)&Ps[wave][li][32 + lg * 8];
#pragma unroll
    for (int d = 0; d < 4; d++) {
      short8 vf0 = *(const short8*)&Vt[d * 16 + li][lg * 8];
      short8 vf1 = *(const short8*)&Vt[d * 16 + li][32 + lg * 8];
      po[d] = mfma16(vf0, pf0, po[d]);
      po[d] = mfma16(vf1, pf1, po[d]);
    }
  }

  // epilogue: lane holds ctx[q=li][d=db*16+4lg+r] -> packed 8B stores
  float rl = 1.0f / l_i;
  unsigned short* cg =
      ctx + (size_t)(b * S_ + qt * 64 + wave * 16 + li) * DM_ + h * DK_;
#pragma unroll
  for (int db = 0; db < 4; db++) {
    uint2 w;
    w.x = pkbf(po[db][0] * rl, po[db][1] * rl);
    w.y = pkbf(po[db][2] * rl, po[db][3] * rl);
    *(uint2*)(cg + db * 16 + lg * 4) = w;
  }
}

// ---------------- launch ----------------
extern "C" void kernel_launch(void* const* d_in, const int* in_sizes, int n_in,
                              void* d_out, int out_size, void* d_ws, size_t ws_size,
                              hipStream_t stream) {
  const float* Q  = (const float*)d_in[0];
  const float* Kx = (const float*)d_in[1];
  const float* V  = (const float*)d_in[2];
  const float* Wq = (const float*)d_in[3];
  const float* bq = (const float*)d_in[4];
  const float* Wk = (const float*)d_in[5];
  const float* bk = (const float*)d_in[6];
  const float* Wv = (const float*)d_in[7];
  const float* bv = (const float*)d_in[8];
  const float* Wo = (const float*)d_in[9];
  const float* bo = (const float*)d_in[10];
  float* out = (float*)d_out;

  char* ws = (char*)d_ws;
  const size_t MB = 1ull << 20;
  unsigned short* Qb  = (unsigned short*)(ws + 0 * MB);
  unsigned short* Kb  = (unsigned short*)(ws + 8 * MB);
  unsigned short* Vb  = (unsigned short*)(ws + 16 * MB);
  unsigned short* Wqb = (unsigned short*)(ws + 24 * MB);
  unsigned short* Wkb = (unsigned short*)(ws + 26 * MB);
  unsigned short* Wvb = (unsigned short*)(ws + 28 * MB);
  unsigned short* Wob = (unsigned short*)(ws + 30 * MB);
  unsigned short* qp  = (unsigned short*)(ws + 32 * MB);
  unsigned short* kp  = (unsigned short*)(ws + 40 * MB);
  unsigned short* vp  = (unsigned short*)(ws + 48 * MB);
  unsigned short* cx  = (unsigned short*)(ws + 56 * MB);  // 64 MB total

  cvt_all<<<16384, 256, 0, stream>>>(Q, Kx, V, Wq, Wk, Wv, Wo,
                                     Qb, Kb, Vb, Wqb, Wkb, Wvb, Wob);

  // Q projection pre-scaled by (1/sqrt(dk)) * log2(e)
  gemm_qkv<<<1536, 256, 0, stream>>>(
      Qb, Kb, Vb, Wqb, Wkb, Wvb, bq, bk, bv, qp, kp, vp, 0.18033688f);

  attn_fwd<<<1024, 256, 0, stream>>>(qp, kp, vp, cx);

  gemm_out<<<512, 256, 0, stream>>>(cx, Wob, bo, out);
}

// Round 6
// 148.208 us; speedup vs baseline: 1.9185x; 1.0258x over previous
//
#include <hip/hip_runtime.h>
#include <hip/hip_bf16.h>
#include <cstdint>
#include <cstddef>
#include <cmath>

typedef __attribute__((ext_vector_type(8))) short short8;
typedef __attribute__((ext_vector_type(4))) short short4_t;
typedef __attribute__((ext_vector_type(4))) float f32x4;
typedef __attribute__((ext_vector_type(16))) float f32x16;

constexpr int B_ = 2, S_ = 2048, H_ = 16, DK_ = 64, DM_ = 1024;

__device__ inline unsigned short f2bf(float x) {
  union { float f; unsigned u; } c; c.f = x;
  unsigned r = c.u + 0x7FFF + ((c.u >> 16) & 1);
  return (unsigned short)(r >> 16);
}

// native 2^x
__device__ inline float ex2(float x) {
#if __has_builtin(__builtin_amdgcn_exp2f)
  return __builtin_amdgcn_exp2f(x);
#else
  return exp2f(x);
#endif
}

// packed f32x2 -> bf16x2 (RNE), single HW op
__device__ inline unsigned pkbf(float lo, float hi) {
  unsigned u;
  asm("v_cvt_pk_bf16_f32 %0, %1, %2" : "=v"(u) : "v"(lo), "v"(hi));
  return u;
}

__device__ inline f32x4 mfma16(short8 a, short8 b, f32x4 c) {
  return __builtin_amdgcn_mfma_f32_16x16x32_bf16(a, b, c, 0, 0, 0);
}
__device__ inline f32x16 mfma32(short8 a, short8 b, f32x16 c) {
  return __builtin_amdgcn_mfma_f32_32x32x16_bf16(a, b, c, 0, 0, 0);
}

// async global->LDS, 16B per lane; LDS dest must be linear (base + lane*16)
__device__ inline void glds16(const unsigned short* g, unsigned short* l) {
  __builtin_amdgcn_global_load_lds(
      (const __attribute__((address_space(1))) unsigned int*)g,
      (__attribute__((address_space(3))) unsigned int*)l, 16, 0, 0);
}

// ---------------- fused f32 -> bf16 convert for all 7 tensors ------------
__global__ __launch_bounds__(256) void cvt_all(
    const float* __restrict__ Q, const float* __restrict__ K,
    const float* __restrict__ V, const float* __restrict__ Wq,
    const float* __restrict__ Wk, const float* __restrict__ Wv,
    const float* __restrict__ Wo, unsigned short* __restrict__ Qb,
    unsigned short* __restrict__ Kb, unsigned short* __restrict__ Vb,
    unsigned short* __restrict__ Wqb, unsigned short* __restrict__ Wkb,
    unsigned short* __restrict__ Wvb, unsigned short* __restrict__ Wob) {
  int bid = blockIdx.x;
  const float* in; unsigned short* out; int off;
  if (bid < 4096)       { in = Q;  out = Qb;  off = bid; }
  else if (bid < 8192)  { in = K;  out = Kb;  off = bid - 4096; }
  else if (bid < 12288) { in = V;  out = Vb;  off = bid - 8192; }
  else if (bid < 13312) { in = Wq; out = Wqb; off = bid - 12288; }
  else if (bid < 14336) { in = Wk; out = Wkb; off = bid - 13312; }
  else if (bid < 15360) { in = Wv; out = Wvb; off = bid - 14336; }
  else                  { in = Wo; out = Wob; off = bid - 15360; }
  int i = off * 256 + threadIdx.x;
  float4 f = ((const float4*)in)[i];
  uint2 o;
  o.x = pkbf(f.x, f.y);
  o.y = pkbf(f.z, f.w);
  ((uint2*)out)[i] = o;
}

// ---------------- bf16 GEMM body: C = (A * Bw^T + bias) * cscale ----------
// fixed 4096x1024x1024, 128x64 tile, 4 waves (2x2, 64x32 each)
__device__ inline void store_out(float* p, float v) { *p = v; }
__device__ inline void store_out(unsigned short* p, float v) { *p = f2bf(v); }

template <typename OUT_T>
__device__ inline void gemm_body(const unsigned short* __restrict__ A,
                                 const unsigned short* __restrict__ Bw,
                                 const float* __restrict__ bias,
                                 OUT_T* __restrict__ C, float cscale,
                                 int bm, int bn) {
  constexpr int Kd = 1024, Nd = 1024;
  __shared__ unsigned short As[128][64];  // 16 KB
  __shared__ unsigned short Bs[64][64];   // 8 KB

  const int tid = threadIdx.x;
  const int lane = tid & 63, wave = tid >> 6;
  const int li = lane & 15, lg = lane >> 4;
  const int wm = wave >> 1, wn = wave & 1;

  const f32x4 zero4 = {0.f, 0.f, 0.f, 0.f};
  f32x4 acc[4][2];
#pragma unroll
  for (int i = 0; i < 4; i++)
#pragma unroll
    for (int j = 0; j < 2; j++) acc[i][j] = zero4;

  const int stg_row = tid >> 3;
  const int stg_col = (tid & 7) * 8;
  const unsigned short* Ag = A + (size_t)(bm * 128 + stg_row) * Kd + stg_col;
  const unsigned short* Bg = Bw + (size_t)(bn * 64 + stg_row) * Kd + stg_col;

  for (int kt = 0; kt < Kd; kt += 64) {
#pragma unroll
    for (int i = 0; i < 4; i++)
      glds16(Ag + (size_t)(i * 32) * Kd + kt, &As[i * 32 + stg_row][stg_col]);
#pragma unroll
    for (int i = 0; i < 2; i++)
      glds16(Bg + (size_t)(i * 32) * Kd + kt, &Bs[i * 32 + stg_row][stg_col]);
    __syncthreads();

    short8 af[4][2], bf[2][2];
#pragma unroll
    for (int kb = 0; kb < 2; kb++) {
#pragma unroll
      for (int i = 0; i < 4; i++)
        af[i][kb] = *(const short8*)&As[wm * 64 + i * 16 + li][kb * 32 + lg * 8];
#pragma unroll
      for (int j = 0; j < 2; j++)
        bf[j][kb] = *(const short8*)&Bs[wn * 32 + j * 16 + li][kb * 32 + lg * 8];
    }
#pragma unroll
    for (int kb = 0; kb < 2; kb++)
#pragma unroll
      for (int i = 0; i < 4; i++)
#pragma unroll
        for (int j = 0; j < 2; j++)
          acc[i][j] = mfma16(af[i][kb], bf[j][kb], acc[i][j]);
    __syncthreads();
  }

#pragma unroll
  for (int j = 0; j < 2; j++) {
    int col = bn * 64 + wn * 32 + j * 16 + li;
    float bv = bias[col];
#pragma unroll
    for (int i = 0; i < 4; i++) {
      int row0 = bm * 128 + wm * 64 + i * 16 + lg * 4;
#pragma unroll
      for (int r = 0; r < 4; r++)
        store_out(&C[(size_t)(row0 + r) * Nd + col], (acc[i][j][r] + bv) * cscale);
    }
  }
}

// 1D grid 1536: xcd=n&7 owns bm in [xcd*4, xcd*4+4) for each z
__global__ __launch_bounds__(256) void gemm_qkv(
    const unsigned short* __restrict__ Aq, const unsigned short* __restrict__ Ak,
    const unsigned short* __restrict__ Av, const unsigned short* __restrict__ Bq,
    const unsigned short* __restrict__ Bk, const unsigned short* __restrict__ Bv,
    const float* __restrict__ bq, const float* __restrict__ bk,
    const float* __restrict__ bv, unsigned short* __restrict__ Cq,
    unsigned short* __restrict__ Ck, unsigned short* __restrict__ Cv,
    float qscale) {
  const int n = blockIdx.x;
  const int xcd = n & 7, m = n >> 3;
  const int z = m >> 6, idx = m & 63;
  const int bm = xcd * 4 + (idx >> 4), bn = idx & 15;
  const unsigned short* A = z == 0 ? Aq : z == 1 ? Ak : Av;
  const unsigned short* Bw = z == 0 ? Bq : z == 1 ? Bk : Bv;
  const float* bi = z == 0 ? bq : z == 1 ? bk : bv;
  unsigned short* C = z == 0 ? Cq : z == 1 ? Ck : Cv;
  gemm_body(A, Bw, bi, C, z == 0 ? qscale : 1.0f, bm, bn);
}

__global__ __launch_bounds__(256) void gemm_out(
    const unsigned short* __restrict__ A, const unsigned short* __restrict__ Bw,
    const float* __restrict__ bias, float* __restrict__ C) {
  const int n = blockIdx.x;
  const int xcd = n & 7, m = n >> 3;
  const int bm = xcd * 4 + (m >> 4), bn = m & 15;
  gemm_body(A, Bw, bias, C, 1.0f, bm, bn);
}

// ---------------- flash attention: 32x32 MFMA, 4 waves x 32 q, KVBLK=64 --
// Swapped QK: sacc = mfma32(K, Q) -> lane (l31,h) holds S[q=l31][key=
// kb*32 + (r&3)+8*(r>>2)+4h]. Row stats: in-lane tree + shfl_xor(32).
// P->B-frag redistribution: pkbf pairs + shfl_xor(32)+select (no LDS).
// PV: ctx^T = mfma32(V^T, P^T). Vt/Ks slot-XOR-swizzled (conflict-free).
__global__ __launch_bounds__(256) void attn_fwd(
    const unsigned short* __restrict__ q, const unsigned short* __restrict__ k,
    const unsigned short* __restrict__ v, unsigned short* __restrict__ ctx) {
  __shared__ unsigned short Ks[2][64][64];   // 16 KB, swizzled 16B slots
  __shared__ unsigned short Vt[64][64];      // [d][key], swizzled, 8 KB

  const int tid = threadIdx.x;
  const int lane = tid & 63, wave = tid >> 6;
  const int l31 = lane & 31, h = lane >> 5;
  const int n = blockIdx.x;
  const int xcd = n & 7, m = n >> 3;
  const int bh = xcd * 4 + (m & 3);
  const int qt = m >> 2;
  const int b = bh >> 4, hd = bh & 15;

  // Q fragments (B-operand): lane needs Q[q=l31][t*16 + h*8 + j]
  const int qrow = qt * 128 + wave * 32 + l31;
  const unsigned short* qg = q + (size_t)(b * S_ + qrow) * DM_ + hd * DK_;
  short8 qf[4];
#pragma unroll
  for (int t = 0; t < 4; t++) qf[t] = *(const short8*)(qg + t * 16 + h * 8);

  f32x16 po[2];
#pragma unroll
  for (int db = 0; db < 2; db++)
#pragma unroll
    for (int r = 0; r < 16; r++) po[db][r] = 0.f;
  float m_i = -1e30f, l_i = 0.f;

  // K staging: linear LDS dest, XOR-swizzled global source (rule #21)
  const int srow = tid >> 3;                 // 0..31
  const int sc = tid & 7;                    // 16B slot
  const int scs = (sc ^ (srow & 7)) * 8;     // swizzled source col
  const unsigned short* kg = k + (size_t)(b * S_) * DM_ + hd * DK_;

  // V staging: 2 keys x 8 d's per thread
  const int vm = tid & 31;                   // key pair index
  const int vkey2 = vm * 2;
  const int vd0 = (tid >> 5) * 8;
  const unsigned short* vg = v + (size_t)(b * S_) * DM_ + hd * DK_;

  const int NT = S_ / 64;

  // prologue: stage K(0), load V(0) to regs
  glds16(kg + (size_t)srow * DM_ + scs, &Ks[0][srow][sc * 8]);
  glds16(kg + (size_t)(32 + srow) * DM_ + scs, &Ks[0][32 + srow][sc * 8]);
  short8 t0, t1;
  {
    const unsigned short* vp = vg + (size_t)vkey2 * DM_ + vd0;
    t0 = *(const short8*)(vp);
    t1 = *(const short8*)(vp + DM_);
  }

  for (int kt = 0; kt < NT; kt++) {
    const int buf = kt & 1;
    // B1: drain OWN staging loads, then barrier
    asm volatile("s_waitcnt vmcnt(0)" ::: "memory");
    __builtin_amdgcn_sched_barrier(0);
    __builtin_amdgcn_s_barrier();
    __builtin_amdgcn_sched_barrier(0);

    // write V(kt) transposed, slot-swizzled, packed u32
#pragma unroll
    for (int j = 0; j < 8; j++) {
      unsigned w = (unsigned)(unsigned short)t0[j] |
                   ((unsigned)(unsigned short)t1[j] << 16);
      int slot = (vm >> 2) ^ j;             // (vkey2>>3) ^ ((vd0+j)&7)
      *(unsigned*)&Vt[vd0 + j][slot * 8 + (vkey2 & 7)] = w;
    }

    // prefetch next tile (in flight across compute; drained at next B1)
    if (kt + 1 < NT) {
      const unsigned short* kgt = kg + (size_t)((kt + 1) * 64) * DM_;
      glds16(kgt + (size_t)srow * DM_ + scs, &Ks[buf ^ 1][srow][sc * 8]);
      glds16(kgt + (size_t)(32 + srow) * DM_ + scs, &Ks[buf ^ 1][32 + srow][sc * 8]);
      const unsigned short* vp = vg + (size_t)((kt + 1) * 64 + vkey2) * DM_ + vd0;
      t0 = *(const short8*)(vp);
      t1 = *(const short8*)(vp + DM_);
    }

    // B2: Vt ds_writes landed
    asm volatile("s_waitcnt lgkmcnt(0)" ::: "memory");
    __builtin_amdgcn_sched_barrier(0);
    __builtin_amdgcn_s_barrier();
    __builtin_amdgcn_sched_barrier(0);

    // S^T = K Q^T (exp2 domain): sacc[kb] = S[q=l31][keys kb*32 + ...]
    f32x16 sacc[2];
#pragma unroll
    for (int kb = 0; kb < 2; kb++)
#pragma unroll
      for (int r = 0; r < 16; r++) sacc[kb][r] = 0.f;
#pragma unroll
    for (int t = 0; t < 4; t++) {
      const int slot = ((t << 1) | h) ^ (l31 & 7);
#pragma unroll
      for (int kb = 0; kb < 2; kb++) {
        short8 kf = *(const short8*)&Ks[buf][kb * 32 + l31][slot * 8];
        sacc[kb] = mfma32(kf, qf[t], sacc[kb]);
      }
    }

    // row max: in-lane tree over 32 + partner half via shfl_xor(32)
    float mx;
    {
      float a = -1e30f, c = -1e30f;
#pragma unroll
      for (int r = 0; r < 16; r += 2) {
        a = fmaxf(a, fmaxf(sacc[0][r], sacc[0][r + 1]));
        c = fmaxf(c, fmaxf(sacc[1][r], sacc[1][r + 1]));
      }
      mx = fmaxf(a, c);
    }
    mx = fmaxf(mx, __shfl_xor(mx, 32));

    // defer-max (T13): skip rescale while growth <= 8
    if (!__all(mx - m_i <= 8.0f)) {
      float mn = fmaxf(m_i, mx);
      float al = ex2(m_i - mn);
      m_i = mn;
      l_i *= al;
#pragma unroll
      for (int db = 0; db < 2; db++)
#pragma unroll
        for (int r = 0; r < 16; r++) po[db][r] *= al;
    }

    // p = exp2(s - m) in place; 4-way partial sums
    float s0 = 0.f, s1 = 0.f, s2 = 0.f, s3 = 0.f;
#pragma unroll
    for (int kb = 0; kb < 2; kb++)
#pragma unroll
      for (int r = 0; r < 16; r += 4) {
        float p0 = ex2(sacc[kb][r] - m_i);
        float p1 = ex2(sacc[kb][r + 1] - m_i);
        float p2 = ex2(sacc[kb][r + 2] - m_i);
        float p3 = ex2(sacc[kb][r + 3] - m_i);
        sacc[kb][r] = p0; sacc[kb][r + 1] = p1;
        sacc[kb][r + 2] = p2; sacc[kb][r + 3] = p3;
        s0 += p0; s1 += p1; s2 += p2; s3 += p3;
      }
    float sum = (s0 + s1) + (s2 + s3);
    sum += __shfl_xor(sum, 32);
    l_i += sum;

    // pack P -> bf16 pairs: u[kb][quad][w] = keys kb*32+8*quad+4h+{2w,2w+1}
    unsigned u[2][4][2];
#pragma unroll
    for (int kb = 0; kb < 2; kb++)
#pragma unroll
      for (int qd = 0; qd < 4; qd++) {
        u[kb][qd][0] = pkbf(sacc[kb][4 * qd], sacc[kb][4 * qd + 1]);
        u[kb][qd][1] = pkbf(sacc[kb][4 * qd + 2], sacc[kb][4 * qd + 3]);
      }

    // per k-step t: B-frag keys 16t+8h+{0..7}; half from partner (lane^32)
#pragma unroll
    for (int t = 0; t < 4; t++) {
      const int kb = t >> 1, qe = (t & 1) * 2;
      unsigned X0 = u[kb][qe][0], X1 = u[kb][qe][1];
      unsigned Y0 = u[kb][qe + 1][0], Y1 = u[kb][qe + 1][1];
      unsigned sX0 = __shfl_xor(X0, 32), sX1 = __shfl_xor(X1, 32);
      unsigned sY0 = __shfl_xor(Y0, 32), sY1 = __shfl_xor(Y1, 32);
      union { unsigned w[4]; short8 v8; } fr;
      fr.w[0] = h ? sY0 : X0;
      fr.w[1] = h ? sY1 : X1;
      fr.w[2] = h ? Y0 : sX0;
      fr.w[3] = h ? Y1 : sX1;
      const int slot = ((t << 1) | h) ^ (l31 & 7);
#pragma unroll
      for (int db = 0; db < 2; db++) {
        short8 vf = *(const short8*)&Vt[db * 32 + l31][slot * 8];
        po[db] = mfma32(vf, fr.v8, po[db]);
      }
    }
  }

  // epilogue: lane holds ctx[q=qrow][d = db*32 + (r&3) + 8*(r>>2) + 4h]
  float rl = 1.0f / l_i;
  unsigned short* cg = ctx + (size_t)(b * S_ + qrow) * DM_ + hd * DK_;
#pragma unroll
  for (int db = 0; db < 2; db++)
#pragma unroll
    for (int rq = 0; rq < 4; rq++) {
      uint2 w2;
      w2.x = pkbf(po[db][4 * rq] * rl, po[db][4 * rq + 1] * rl);
      w2.y = pkbf(po[db][4 * rq + 2] * rl, po[db][4 * rq + 3] * rl);
      *(uint2*)(cg + db * 32 + 8 * rq + 4 * h) = w2;
    }
}

// ---------------- launch ----------------
extern "C" void kernel_launch(void* const* d_in, const int* in_sizes, int n_in,
                              void* d_out, int out_size, void* d_ws, size_t ws_size,
                              hipStream_t stream) {
  const float* Q  = (const float*)d_in[0];
  const float* Kx = (const float*)d_in[1];
  const float* V  = (const float*)d_in[2];
  const float* Wq = (const float*)d_in[3];
  const float* bq = (const float*)d_in[4];
  const float* Wk = (const float*)d_in[5];
  const float* bk = (const float*)d_in[6];
  const float* Wv = (const float*)d_in[7];
  const float* bv = (const float*)d_in[8];
  const float* Wo = (const float*)d_in[9];
  const float* bo = (const float*)d_in[10];
  float* out = (float*)d_out;

  char* ws = (char*)d_ws;
  const size_t MB = 1ull << 20;
  unsigned short* Qb  = (unsigned short*)(ws + 0 * MB);
  unsigned short* Kb  = (unsigned short*)(ws + 8 * MB);
  unsigned short* Vb  = (unsigned short*)(ws + 16 * MB);
  unsigned short* Wqb = (unsigned short*)(ws + 24 * MB);
  unsigned short* Wkb = (unsigned short*)(ws + 26 * MB);
  unsigned short* Wvb = (unsigned short*)(ws + 28 * MB);
  unsigned short* Wob = (unsigned short*)(ws + 30 * MB);
  unsigned short* qp  = (unsigned short*)(ws + 32 * MB);
  unsigned short* kp  = (unsigned short*)(ws + 40 * MB);
  unsigned short* vp  = (unsigned short*)(ws + 48 * MB);
  unsigned short* cx  = (unsigned short*)(ws + 56 * MB);  // 64 MB total

  cvt_all<<<16384, 256, 0, stream>>>(Q, Kx, V, Wq, Wk, Wv, Wo,
                                     Qb, Kb, Vb, Wqb, Wkb, Wvb, Wob);

  // Q projection pre-scaled by (1/sqrt(dk)) * log2(e)
  gemm_qkv<<<1536, 256, 0, stream>>>(
      Qb, Kb, Vb, Wqb, Wkb, Wvb, bq, bk, bv, qp, kp, vp, 0.18033688f);

  attn_fwd<<<512, 256, 0, stream>>>(qp, kp, vp, cx);

  gemm_out<<<512, 256, 0, stream>>>(cx, Wob, bo, out);
}

// Round 7
// 138.107 us; speedup vs baseline: 2.0588x; 1.0731x over previous
//
#include <hip/hip_runtime.h>
#include <hip/hip_bf16.h>
#include <cstdint>
#include <cstddef>
#include <cmath>

typedef __attribute__((ext_vector_type(8))) short short8;
typedef __attribute__((ext_vector_type(4))) short short4_t;
typedef __attribute__((ext_vector_type(4))) float f32x4;
typedef __attribute__((ext_vector_type(16))) float f32x16;

constexpr int B_ = 2, S_ = 2048, H_ = 16, DK_ = 64, DM_ = 1024;

__device__ inline unsigned short f2bf(float x) {
  union { float f; unsigned u; } c; c.f = x;
  unsigned r = c.u + 0x7FFF + ((c.u >> 16) & 1);
  return (unsigned short)(r >> 16);
}

// native 2^x
__device__ inline float ex2(float x) {
#if __has_builtin(__builtin_amdgcn_exp2f)
  return __builtin_amdgcn_exp2f(x);
#else
  return exp2f(x);
#endif
}

// packed f32x2 -> bf16x2 (RNE), single HW op
__device__ inline unsigned pkbf(float lo, float hi) {
  unsigned u;
  asm("v_cvt_pk_bf16_f32 %0, %1, %2" : "=v"(u) : "v"(lo), "v"(hi));
  return u;
}

__device__ inline f32x4 mfma16(short8 a, short8 b, f32x4 c) {
  return __builtin_amdgcn_mfma_f32_16x16x32_bf16(a, b, c, 0, 0, 0);
}
__device__ inline f32x16 mfma32(short8 a, short8 b, f32x16 c) {
  return __builtin_amdgcn_mfma_f32_32x32x16_bf16(a, b, c, 0, 0, 0);
}

// async global->LDS, 16B per lane; LDS dest must be linear (base + lane*16)
__device__ inline void glds16(const unsigned short* g, unsigned short* l) {
  __builtin_amdgcn_global_load_lds(
      (const __attribute__((address_space(1))) unsigned int*)g,
      (__attribute__((address_space(3))) unsigned int*)l, 16, 0, 0);
}

// ---------------- fused f32 -> bf16 convert for all 7 tensors ------------
__global__ __launch_bounds__(256) void cvt_all(
    const float* __restrict__ Q, const float* __restrict__ K,
    const float* __restrict__ V, const float* __restrict__ Wq,
    const float* __restrict__ Wk, const float* __restrict__ Wv,
    const float* __restrict__ Wo, unsigned short* __restrict__ Qb,
    unsigned short* __restrict__ Kb, unsigned short* __restrict__ Vb,
    unsigned short* __restrict__ Wqb, unsigned short* __restrict__ Wkb,
    unsigned short* __restrict__ Wvb, unsigned short* __restrict__ Wob) {
  int bid = blockIdx.x;
  const float* in; unsigned short* out; int off;
  if (bid < 4096)       { in = Q;  out = Qb;  off = bid; }
  else if (bid < 8192)  { in = K;  out = Kb;  off = bid - 4096; }
  else if (bid < 12288) { in = V;  out = Vb;  off = bid - 8192; }
  else if (bid < 13312) { in = Wq; out = Wqb; off = bid - 12288; }
  else if (bid < 14336) { in = Wk; out = Wkb; off = bid - 13312; }
  else if (bid < 15360) { in = Wv; out = Wvb; off = bid - 14336; }
  else                  { in = Wo; out = Wob; off = bid - 15360; }
  int i = off * 256 + threadIdx.x;
  float4 f = ((const float4*)in)[i];
  uint2 o;
  o.x = pkbf(f.x, f.y);
  o.y = pkbf(f.z, f.w);
  ((uint2*)out)[i] = o;
}

// ---------------- bf16 GEMM body: C = (A * Bw^T + bias) * cscale ----------
__device__ inline void store_out(float* p, float v) { *p = v; }
__device__ inline void store_out(unsigned short* p, float v) { *p = f2bf(v); }

template <typename OUT_T>
__device__ inline void gemm_body(const unsigned short* __restrict__ A,
                                 const unsigned short* __restrict__ Bw,
                                 const float* __restrict__ bias,
                                 OUT_T* __restrict__ C, float cscale,
                                 int bm, int bn) {
  constexpr int Kd = 1024, Nd = 1024;
  __shared__ unsigned short As[128][64];  // 16 KB
  __shared__ unsigned short Bs[64][64];   // 8 KB

  const int tid = threadIdx.x;
  const int lane = tid & 63, wave = tid >> 6;
  const int li = lane & 15, lg = lane >> 4;
  const int wm = wave >> 1, wn = wave & 1;

  const f32x4 zero4 = {0.f, 0.f, 0.f, 0.f};
  f32x4 acc[4][2];
#pragma unroll
  for (int i = 0; i < 4; i++)
#pragma unroll
    for (int j = 0; j < 2; j++) acc[i][j] = zero4;

  const int stg_row = tid >> 3;
  const int stg_col = (tid & 7) * 8;
  const unsigned short* Ag = A + (size_t)(bm * 128 + stg_row) * Kd + stg_col;
  const unsigned short* Bg = Bw + (size_t)(bn * 64 + stg_row) * Kd + stg_col;

  for (int kt = 0; kt < Kd; kt += 64) {
#pragma unroll
    for (int i = 0; i < 4; i++)
      glds16(Ag + (size_t)(i * 32) * Kd + kt, &As[i * 32 + stg_row][stg_col]);
#pragma unroll
    for (int i = 0; i < 2; i++)
      glds16(Bg + (size_t)(i * 32) * Kd + kt, &Bs[i * 32 + stg_row][stg_col]);
    __syncthreads();

    short8 af[4][2], bf[2][2];
#pragma unroll
    for (int kb = 0; kb < 2; kb++) {
#pragma unroll
      for (int i = 0; i < 4; i++)
        af[i][kb] = *(const short8*)&As[wm * 64 + i * 16 + li][kb * 32 + lg * 8];
#pragma unroll
      for (int j = 0; j < 2; j++)
        bf[j][kb] = *(const short8*)&Bs[wn * 32 + j * 16 + li][kb * 32 + lg * 8];
    }
#pragma unroll
    for (int kb = 0; kb < 2; kb++)
#pragma unroll
      for (int i = 0; i < 4; i++)
#pragma unroll
        for (int j = 0; j < 2; j++)
          acc[i][j] = mfma16(af[i][kb], bf[j][kb], acc[i][j]);
    __syncthreads();
  }

#pragma unroll
  for (int j = 0; j < 2; j++) {
    int col = bn * 64 + wn * 32 + j * 16 + li;
    float bv = bias[col];
#pragma unroll
    for (int i = 0; i < 4; i++) {
      int row0 = bm * 128 + wm * 64 + i * 16 + lg * 4;
#pragma unroll
      for (int r = 0; r < 4; r++)
        store_out(&C[(size_t)(row0 + r) * Nd + col], (acc[i][j][r] + bv) * cscale);
    }
  }
}

// 1D grid 1536: xcd=n&7 owns bm in [xcd*4, xcd*4+4) for each z
__global__ __launch_bounds__(256) void gemm_qkv(
    const unsigned short* __restrict__ Aq, const unsigned short* __restrict__ Ak,
    const unsigned short* __restrict__ Av, const unsigned short* __restrict__ Bq,
    const unsigned short* __restrict__ Bk, const unsigned short* __restrict__ Bv,
    const float* __restrict__ bq, const float* __restrict__ bk,
    const float* __restrict__ bv, unsigned short* __restrict__ Cq,
    unsigned short* __restrict__ Ck, unsigned short* __restrict__ Cv,
    float qscale) {
  const int n = blockIdx.x;
  const int xcd = n & 7, m = n >> 3;
  const int z = m >> 6, idx = m & 63;
  const int bm = xcd * 4 + (idx >> 4), bn = idx & 15;
  const unsigned short* A = z == 0 ? Aq : z == 1 ? Ak : Av;
  const unsigned short* Bw = z == 0 ? Bq : z == 1 ? Bk : Bv;
  const float* bi = z == 0 ? bq : z == 1 ? bk : bv;
  unsigned short* C = z == 0 ? Cq : z == 1 ? Ck : Cv;
  gemm_body(A, Bw, bi, C, z == 0 ? qscale : 1.0f, bm, bn);
}

__global__ __launch_bounds__(256) void gemm_out(
    const unsigned short* __restrict__ A, const unsigned short* __restrict__ Bw,
    const float* __restrict__ bias, float* __restrict__ C) {
  const int n = blockIdx.x;
  const int xcd = n & 7, m = n >> 3;
  const int bm = xcd * 4 + (m >> 4), bn = m & 15;
  gemm_body(A, Bw, bias, C, 1.0f, bm, bn);
}

// ---------------- flash attention: 32x32 MFMA, KVBLK=128, 1 barrier/tile --
struct V4 { short8 v[4]; };

// One KV tile (128 keys). Single barrier per tile; K glds + V reg-loads for
// tile kt+1 stay in flight across the whole compute phase.
// Safety of 1 barrier: Vt[buf] rewritten at t was last read at t-2, and all
// waves passed barrier(t-1) AFTER compute(t-1) (so after compute(t-2) too).
// Ks[buf^1] restaged only after barrier(t), when compute(t-1) is done.
__device__ __forceinline__ void attn_tile_step(
    int kt, int buf, int NT,
    const unsigned short* kg, const unsigned short* vg,
    unsigned short* KsAll, unsigned short* VtAll,
    int srow, int sc, int scs, int key2, int dq,
    const short8* qf, int l31, int h,
    V4& vc, V4& vn, f32x16* po, float& m_i, float& l_i) {
  unsigned short* KsB = KsAll + buf * (128 * 64);
  unsigned short* VtB = VtAll + buf * (64 * 128);
  unsigned short* KsO = KsAll + (buf ^ 1) * (128 * 64);

  // drain my staging loads: K(kt) glds landed in KsB, V(kt) in vc
  asm volatile("s_waitcnt vmcnt(0)" ::: "memory");
  __builtin_amdgcn_sched_barrier(0);

  // write V(kt) transposed+swizzled: Vt[d][key], slot16 xor (row&15)
#pragma unroll
  for (int j = 0; j < 16; j++) {
    const int half = j >> 3, jj = j & 7;
    unsigned w = (unsigned)(unsigned short)vc.v[half][jj] |
                 ((unsigned)(unsigned short)vc.v[2 + half][jj] << 16);
    const int slot = (key2 >> 3) ^ j;  // j == row&15
    *(unsigned*)&VtB[(dq * 16 + j) * 128 + slot * 8 + (key2 & 7)] = w;
  }

  // issue V(kt+1) reg loads (fly across barrier + compute)
  if (kt + 1 < NT) {
    const unsigned short* vp =
        vg + (size_t)((kt + 1) * 128 + key2) * DM_ + dq * 16;
    vn.v[0] = *(const short8*)(vp);
    vn.v[1] = *(const short8*)(vp + 8);
    vn.v[2] = *(const short8*)(vp + DM_);
    vn.v[3] = *(const short8*)(vp + DM_ + 8);
  }

  // my Vt writes done -> barrier: tile kt LDS fully visible to all waves
  asm volatile("s_waitcnt lgkmcnt(0)" ::: "memory");
  __builtin_amdgcn_sched_barrier(0);
  __builtin_amdgcn_s_barrier();
  __builtin_amdgcn_sched_barrier(0);

  // issue K(kt+1) glds into other buffer (safe: compute(kt-1) done everywhere)
  if (kt + 1 < NT) {
    const unsigned short* kgt = kg + (size_t)((kt + 1) * 128) * DM_;
#pragma unroll
    for (int i = 0; i < 4; i++)
      glds16(kgt + (size_t)(i * 32 + srow) * DM_ + scs,
             &KsO[(i * 32 + srow) * 64 + sc * 8]);
  }
  __builtin_amdgcn_sched_barrier(0);

  // ---- compute tile kt ----
  // S^T = K Q^T: sacc[kb][r] = S[q=l31][key = kb*32 + (r&3)+8*(r>>2)+4h]
  f32x16 sacc[4];
#pragma unroll
  for (int kb = 0; kb < 4; kb++)
#pragma unroll
    for (int r = 0; r < 16; r++) sacc[kb][r] = 0.f;

  __builtin_amdgcn_s_setprio(1);
#pragma unroll
  for (int tq = 0; tq < 4; tq++) {
    const int sl = ((((tq << 1) | h) ^ (l31 & 7))) * 8;
#pragma unroll
    for (int kb = 0; kb < 4; kb++) {
      short8 kf = *(const short8*)&KsB[(kb * 32 + l31) * 64 + sl];
      sacc[kb] = mfma32(kf, qf[tq], sacc[kb]);
    }
  }
  __builtin_amdgcn_s_setprio(0);

  // row max over 128 keys: in-lane tree + partner half
  float mx = -1e30f;
#pragma unroll
  for (int kb = 0; kb < 4; kb++)
#pragma unroll
    for (int r = 0; r < 16; r += 4)
      mx = fmaxf(mx, fmaxf(fmaxf(sacc[kb][r], sacc[kb][r + 1]),
                           fmaxf(sacc[kb][r + 2], sacc[kb][r + 3])));
  mx = fmaxf(mx, __shfl_xor(mx, 32));

  // defer-max (T13): skip rescale while growth <= 8
  if (!__all(mx - m_i <= 8.0f)) {
    float mn = fmaxf(m_i, mx);
    float al = ex2(m_i - mn);
    m_i = mn;
    l_i *= al;
#pragma unroll
    for (int db = 0; db < 2; db++)
#pragma unroll
      for (int r = 0; r < 16; r++) po[db][r] *= al;
  }

  // per 32-key block: exp, partial sums, pack, PV (limits register liveness)
  float s0 = 0.f, s1 = 0.f, s2 = 0.f, s3 = 0.f;
#pragma unroll
  for (int kb = 0; kb < 4; kb++) {
#pragma unroll
    for (int r = 0; r < 16; r += 4) {
      float p0 = ex2(sacc[kb][r] - m_i);
      float p1 = ex2(sacc[kb][r + 1] - m_i);
      float p2 = ex2(sacc[kb][r + 2] - m_i);
      float p3 = ex2(sacc[kb][r + 3] - m_i);
      sacc[kb][r] = p0; sacc[kb][r + 1] = p1;
      sacc[kb][r + 2] = p2; sacc[kb][r + 3] = p3;
      s0 += p0; s1 += p1; s2 += p2; s3 += p3;
    }
    unsigned u[4][2];
#pragma unroll
    for (int qd = 0; qd < 4; qd++) {
      u[qd][0] = pkbf(sacc[kb][4 * qd], sacc[kb][4 * qd + 1]);
      u[qd][1] = pkbf(sacc[kb][4 * qd + 2], sacc[kb][4 * qd + 3]);
    }
    // PV k-steps tp = 2kb, 2kb+1: B-frag keys 16tp+8h+{0..7}
#pragma unroll
    for (int tt = 0; tt < 2; tt++) {
      const int tp = 2 * kb + tt, qe = tt * 2;
      unsigned X0 = u[qe][0], X1 = u[qe][1];
      unsigned Y0 = u[qe + 1][0], Y1 = u[qe + 1][1];
      unsigned sX0 = __shfl_xor(X0, 32), sX1 = __shfl_xor(X1, 32);
      unsigned sY0 = __shfl_xor(Y0, 32), sY1 = __shfl_xor(Y1, 32);
      union { unsigned w[4]; short8 v8; } fr;
      fr.w[0] = h ? sY0 : X0;
      fr.w[1] = h ? sY1 : X1;
      fr.w[2] = h ? Y0 : sX0;
      fr.w[3] = h ? Y1 : sX1;
      const int slbase = (tp << 1) | h;
#pragma unroll
      for (int db = 0; db < 2; db++) {
        const int row = db * 32 + l31;
        short8 vf = *(const short8*)
            &VtB[row * 128 + (slbase ^ (l31 & 15)) * 8];
        po[db] = mfma32(vf, fr.v8, po[db]);
      }
    }
  }
  float sum = (s0 + s1) + (s2 + s3);
  sum += __shfl_xor(sum, 32);
  l_i += sum;
}

__global__ __launch_bounds__(256, 2) void attn_fwd(
    const unsigned short* __restrict__ q, const unsigned short* __restrict__ k,
    const unsigned short* __restrict__ v, unsigned short* __restrict__ ctx) {
  __shared__ unsigned short Ks[2][128][64];   // 32 KB, swizzled 8 slots/row
  __shared__ unsigned short Vt[2][64][128];   // 32 KB, swizzled 16 slots/row

  const int tid = threadIdx.x;
  const int lane = tid & 63, wave = tid >> 6;
  const int l31 = lane & 31, h = lane >> 5;
  const int n = blockIdx.x;
  const int xcd = n & 7, m = n >> 3;
  const int bh = xcd * 4 + (m & 3);
  const int qt = m >> 2;                      // 0..15 (qtile = 128)
  const int b = bh >> 4, hd = bh & 15;

  // Q fragments (B-operand): lane needs Q[q=l31][tq*16 + h*8 + j]
  const int qrow = qt * 128 + wave * 32 + l31;
  const unsigned short* qg = q + (size_t)(b * S_ + qrow) * DM_ + hd * DK_;
  short8 qf[4];
#pragma unroll
  for (int t = 0; t < 4; t++) qf[t] = *(const short8*)(qg + t * 16 + h * 8);

  f32x16 po[2];
#pragma unroll
  for (int db = 0; db < 2; db++)
#pragma unroll
    for (int r = 0; r < 16; r++) po[db][r] = 0.f;
  float m_i = -1e30f, l_i = 0.f;

  // K staging geometry (4 glds16/thread/tile; rows srow+{0,32,64,96})
  const int srow = tid >> 3, sc = tid & 7;
  const int scs = (sc ^ (srow & 7)) * 8;      // pre-swizzled source col
  const unsigned short* kg = k + (size_t)(b * S_) * DM_ + hd * DK_;

  // V staging geometry: 2 keys x 16 d's per thread (dq = wave)
  const int key2 = (tid & 63) * 2, dq = tid >> 6;
  const unsigned short* vg = v + (size_t)(b * S_) * DM_ + hd * DK_;

  const int NT = S_ / 128;  // 16

  // prologue: stage K(0), load V(0)
#pragma unroll
  for (int i = 0; i < 4; i++)
    glds16(kg + (size_t)(i * 32 + srow) * DM_ + scs,
           &Ks[0][i * 32 + srow][sc * 8]);
  V4 va, vb;
  {
    const unsigned short* vp = vg + (size_t)key2 * DM_ + dq * 16;
    va.v[0] = *(const short8*)(vp);
    va.v[1] = *(const short8*)(vp + 8);
    va.v[2] = *(const short8*)(vp + DM_);
    va.v[3] = *(const short8*)(vp + DM_ + 8);
  }

  unsigned short* KsAll = &Ks[0][0][0];
  unsigned short* VtAll = &Vt[0][0][0];
  for (int it = 0; it < NT; it += 2) {
    attn_tile_step(it, 0, NT, kg, vg, KsAll, VtAll, srow, sc, scs, key2, dq,
                   qf, l31, h, va, vb, po, m_i, l_i);
    attn_tile_step(it + 1, 1, NT, kg, vg, KsAll, VtAll, srow, sc, scs, key2,
                   dq, qf, l31, h, vb, va, po, m_i, l_i);
  }

  // epilogue: lane holds ctx[q=qrow][d = db*32 + 8rq + 4h + {0..3}]
  float rl = 1.0f / l_i;
  unsigned short* cg = ctx + (size_t)(b * S_ + qrow) * DM_ + hd * DK_;
#pragma unroll
  for (int db = 0; db < 2; db++)
#pragma unroll
    for (int rq = 0; rq < 4; rq++) {
      uint2 w2;
      w2.x = pkbf(po[db][4 * rq] * rl, po[db][4 * rq + 1] * rl);
      w2.y = pkbf(po[db][4 * rq + 2] * rl, po[db][4 * rq + 3] * rl);
      *(uint2*)(cg + db * 32 + 8 * rq + 4 * h) = w2;
    }
}

// ---------------- launch ----------------
extern "C" void kernel_launch(void* const* d_in, const int* in_sizes, int n_in,
                              void* d_out, int out_size, void* d_ws, size_t ws_size,
                              hipStream_t stream) {
  const float* Q  = (const float*)d_in[0];
  const float* Kx = (const float*)d_in[1];
  const float* V  = (const float*)d_in[2];
  const float* Wq = (const float*)d_in[3];
  const float* bq = (const float*)d_in[4];
  const float* Wk = (const float*)d_in[5];
  const float* bk = (const float*)d_in[6];
  const float* Wv = (const float*)d_in[7];
  const float* bv = (const float*)d_in[8];
  const float* Wo = (const float*)d_in[9];
  const float* bo = (const float*)d_in[10];
  float* out = (float*)d_out;

  char* ws = (char*)d_ws;
  const size_t MB = 1ull << 20;
  unsigned short* Qb  = (unsigned short*)(ws + 0 * MB);
  unsigned short* Kb  = (unsigned short*)(ws + 8 * MB);
  unsigned short* Vb  = (unsigned short*)(ws + 16 * MB);
  unsigned short* Wqb = (unsigned short*)(ws + 24 * MB);
  unsigned short* Wkb = (unsigned short*)(ws + 26 * MB);
  unsigned short* Wvb = (unsigned short*)(ws + 28 * MB);
  unsigned short* Wob = (unsigned short*)(ws + 30 * MB);
  unsigned short* qp  = (unsigned short*)(ws + 32 * MB);
  unsigned short* kp  = (unsigned short*)(ws + 40 * MB);
  unsigned short* vp  = (unsigned short*)(ws + 48 * MB);
  unsigned short* cx  = (unsigned short*)(ws + 56 * MB);  // 64 MB total

  cvt_all<<<16384, 256, 0, stream>>>(Q, Kx, V, Wq, Wk, Wv, Wo,
                                     Qb, Kb, Vb, Wqb, Wkb, Wvb, Wob);

  // Q projection pre-scaled by (1/sqrt(dk)) * log2(e)
  gemm_qkv<<<1536, 256, 0, stream>>>(
      Qb, Kb, Vb, Wqb, Wkb, Wvb, bq, bk, bv, qp, kp, vp, 0.18033688f);

  attn_fwd<<<512, 256, 0, stream>>>(qp, kp, vp, cx);

  gemm_out<<<512, 256, 0, stream>>>(cx, Wob, bo, out);
}